// Round 1
// baseline (618.849 us; speedup 1.0000x reference)
//
#include <hip/hip_runtime.h>

typedef unsigned short u16;
using bf16x8 = __attribute__((ext_vector_type(8))) short;
using f32x4  = __attribute__((ext_vector_type(4))) float;

#define SIB_SCALE_F 0.04419417382415922f   // 1/sqrt(512)

__device__ __forceinline__ u16 f2b(float f) {
  unsigned u = __builtin_bit_cast(unsigned, f);
  return (u16)((u + 0x7FFFu + ((u >> 16) & 1u)) >> 16);   // RNE
}

__device__ __forceinline__ float wred(float v) {
  #pragma unroll
  for (int m = 1; m < 64; m <<= 1) v += __shfl_xor(v, m);
  return v;
}

__device__ __forceinline__ void gload16(const void* g, void* l) {
  __builtin_amdgcn_global_load_lds(
      (const __attribute__((address_space(1))) unsigned int*)g,
      (__attribute__((address_space(3))) unsigned int*)l, 16, 0, 0);
}

// ---------------------------------------------------------------------------
// bf16 MFMA GEMM: C[M,N] = A[M,K] @ B[N,K]^T + bscale*bias[N]
// 128x128 tile, BK=32, 4 waves (2x2), 64x64 per wave (4x4 frags of 16x16).
// global_load_lds(16B) staging with XOR slot swizzle (pre-swizzled source).
// M%128==0, N%128==0, K%32==0 required (all call sites satisfy this).
// ---------------------------------------------------------------------------
__global__ __launch_bounds__(256) void gemm_bf16_bt(
    const u16* __restrict__ A, const u16* __restrict__ B,
    const float* __restrict__ bias, float bscale,
    float* __restrict__ C, u16* __restrict__ Cb,
    int M, int N, int K)
{
  __shared__ u16 ldsA[128 * 32];
  __shared__ u16 ldsB[128 * 32];
  const int t = threadIdx.x;
  const int w = t >> 6;
  const int lane = t & 63;
  const int wr = w >> 1, wc = w & 1;
  const int bm = blockIdx.x * 128, bn = blockIdx.y * 128;
  const int r16 = lane & 15, ks = lane >> 4;
  const int srow = t >> 2, sslot = t & 3;

  f32x4 acc[4][4];
  #pragma unroll
  for (int m = 0; m < 4; ++m)
    #pragma unroll
    for (int n = 0; n < 4; ++n) {
      f32x4 z = {0.f, 0.f, 0.f, 0.f};
      acc[m][n] = z;
    }

  for (int k0 = 0; k0 < K; k0 += 32) {
    if (k0) __syncthreads();
    #pragma unroll
    for (int i = 0; i < 2; ++i) {
      const int row = srow + i * 64;
      const int sl = sslot ^ ((row >> 1) & 3);     // source pre-swizzle
      gload16(A + (size_t)(bm + row) * K + k0 + sl * 8,
              ldsA + (i * 2048 + w * 512));
      gload16(B + (size_t)(bn + row) * K + k0 + sl * 8,
              ldsB + (i * 2048 + w * 512));
    }
    __syncthreads();   // compiler drains vmcnt(0) before s_barrier

    bf16x8 af[4], bfr[4];
    #pragma unroll
    for (int m = 0; m < 4; ++m) {
      const int row = wr * 64 + m * 16 + r16;
      af[m] = *(const bf16x8*)(ldsA + row * 32 + ((ks ^ ((row >> 1) & 3)) << 3));
    }
    #pragma unroll
    for (int n = 0; n < 4; ++n) {
      const int row = wc * 64 + n * 16 + r16;
      bfr[n] = *(const bf16x8*)(ldsB + row * 32 + ((ks ^ ((row >> 1) & 3)) << 3));
    }
    #pragma unroll
    for (int m = 0; m < 4; ++m)
      #pragma unroll
      for (int n = 0; n < 4; ++n)
        acc[m][n] = __builtin_amdgcn_mfma_f32_16x16x32_bf16(af[m], bfr[n], acc[m][n], 0, 0, 0);
  }

  // epilogue: C/D layout col = lane&15, row = (lane>>4)*4 + reg
  #pragma unroll
  for (int m = 0; m < 4; ++m) {
    const int grow0 = bm + wr * 64 + m * 16 + ks * 4;
    #pragma unroll
    for (int n = 0; n < 4; ++n) {
      const int gcol = bn + wc * 64 + n * 16 + r16;
      const float bv = bias ? bias[gcol] * bscale : 0.f;
      #pragma unroll
      for (int r = 0; r < 4; ++r) {
        const float v = acc[m][n][r] + bv;
        const size_t idx = (size_t)(grow0 + r) * N + gcol;
        C[idx] = v;
        if (Cb) Cb[idx] = f2b(v);
      }
    }
  }
}

// ---------------------------------------------------------------------------
// fp32 SGEMM (policy path, numerically sensitive): C = A@B^T + bias
// 64x64 tile, BK=16, 256 threads, 4x4 per thread. M%64==0,N%64==0,K%16==0.
// ---------------------------------------------------------------------------
__global__ __launch_bounds__(256) void sgemm_bt(
    const float* __restrict__ A, const float* __restrict__ B,
    const float* __restrict__ bias,
    float* __restrict__ C, int M, int N, int K)
{
  __shared__ float As[16][68];   // +4 pad: conflict-free stores
  __shared__ float Bs[16][68];
  const int t = threadIdx.x;
  const int tx = t & 15, ty = t >> 4;
  const int bm = blockIdx.x * 64, bn = blockIdx.y * 64;
  float acc[4][4] = {};
  for (int k0 = 0; k0 < K; k0 += 16) {
    if (k0) __syncthreads();
    #pragma unroll
    for (int i = 0; i < 4; ++i) {
      const int idx = t + i * 256;
      const int r = idx >> 4, kk = idx & 15;
      As[kk][r] = A[(size_t)(bm + r) * K + k0 + kk];
      Bs[kk][r] = B[(size_t)(bn + r) * K + k0 + kk];
    }
    __syncthreads();
    #pragma unroll
    for (int kk = 0; kk < 16; ++kk) {
      const float4 av = *(const float4*)&As[kk][ty * 4];
      const float4 bv = *(const float4*)&Bs[kk][tx * 4];
      const float ar[4] = {av.x, av.y, av.z, av.w};
      const float br[4] = {bv.x, bv.y, bv.z, bv.w};
      #pragma unroll
      for (int i = 0; i < 4; ++i)
        #pragma unroll
        for (int j = 0; j < 4; ++j)
          acc[i][j] += ar[i] * br[j];
    }
  }
  #pragma unroll
  for (int i = 0; i < 4; ++i) {
    const int grow = bm + ty * 4 + i;
    #pragma unroll
    for (int j = 0; j < 4; ++j) {
      const int gcol = bn + tx * 4 + j;
      C[(size_t)grow * N + gcol] = acc[i][j] + bias[gcol];
    }
  }
}

// ---------------------------------------------------------------------------
// policy input: X[n, 0:512] = LN(S[n]/M + 0.01*dep_l)*g+b ; X[n,512:640]=pde_l
// wave per row, 4 rows/block
// ---------------------------------------------------------------------------
__global__ __launch_bounds__(256) void mean_ln_concat(
    const float* __restrict__ S, float invM,
    const float* __restrict__ depl, const float* __restrict__ pdel,
    const float* __restrict__ g, const float* __restrict__ b,
    float* __restrict__ X)
{
  const int wid = threadIdx.x >> 6, lane = threadIdx.x & 63;
  const int n = blockIdx.x * 4 + wid;
  const float* Sr = S + (size_t)n * 512;
  const int c0 = lane * 8;
  float x[8];
  float s = 0.f, sq = 0.f;
  #pragma unroll
  for (int i = 0; i < 8; ++i) {
    const float v = Sr[c0 + i] * invM + 0.01f * depl[c0 + i];
    x[i] = v; s += v; sq += v * v;
  }
  s = wred(s); sq = wred(sq);
  const float mean = s * (1.f / 512.f);
  const float var = sq * (1.f / 512.f) - mean * mean;
  const float rs = rsqrtf(var + 1e-5f);
  float* Xr = X + (size_t)n * 640;
  #pragma unroll
  for (int i = 0; i < 8; ++i) {
    const int c = c0 + i;
    Xr[c] = (x[i] - mean) * rs * g[c] + b[c];
  }
  Xr[512 + lane * 2]     = pdel[lane * 2];
  Xr[512 + lane * 2 + 1] = pdel[lane * 2 + 1];
}

template <int C>
__global__ __launch_bounds__(256) void ln_relu(
    float* __restrict__ X, const float* __restrict__ g, const float* __restrict__ b)
{
  constexpr int E = C / 64;
  const int wid = threadIdx.x >> 6, lane = threadIdx.x & 63;
  const int n = blockIdx.x * 4 + wid;
  float* Xr = X + (size_t)n * C;
  float x[E];
  float s = 0.f, sq = 0.f;
  #pragma unroll
  for (int i = 0; i < E; ++i) {
    x[i] = Xr[lane * E + i]; s += x[i]; sq += x[i] * x[i];
  }
  s = wred(s); sq = wred(sq);
  const float mean = s * (1.f / (float)C);
  const float var = sq * (1.f / (float)C) - mean * mean;
  const float rs = rsqrtf(var + 1e-5f);
  #pragma unroll
  for (int i = 0; i < E; ++i) {
    const int c = lane * E + i;
    Xr[c] = fmaxf((x[i] - mean) * rs * g[c] + b[c], 0.f);
  }
}

__global__ __launch_bounds__(256) void policy_reduce(
    const float* __restrict__ Y2, const float* __restrict__ pw,
    const float* __restrict__ pb, float* __restrict__ psum)
{
  __shared__ float part[4];
  const int wid = threadIdx.x >> 6, lane = threadIdx.x & 63;
  const int n = blockIdx.x * 4 + wid;
  const float* r = Y2 + (size_t)n * 128;
  float z = r[lane * 2] * pw[lane * 2] + r[lane * 2 + 1] * pw[lane * 2 + 1];
  z = wred(z);
  if (lane == 0) {
    const float p = 1.f / (1.f + expf(-(z + pb[0])));
    part[wid] = fminf(fmaxf(p, 1e-7f), 1.f - 1e-7f);
  }
  __syncthreads();
  if (threadIdx.x == 0)
    atomicAdd(psum, part[0] + part[1] + part[2] + part[3]);
}

__global__ void finalize_coef(const float* __restrict__ psum, float* __restrict__ coef)
{
  float alive = 1.f, cnt = 1.f;
  #pragma unroll
  for (int l = 0; l < 3; ++l) {
    const float pm = psum[l] * (1.f / 4096.f);
    if (!(pm >= 0.5f)) alive = 0.f;
    coef[l] = alive;
    cnt += alive * (float)(2 << l);
  }
  coef[3] = 1.f / fmaxf(cnt, 1e-8f);
}

__global__ __launch_bounds__(256) void pool_to_bf16(
    const float* __restrict__ h0, const float* __restrict__ S1,
    const float* __restrict__ S2, const float* __restrict__ S3,
    const float* __restrict__ coef, u16* __restrict__ P)
{
  const int idx = blockIdx.x * 256 + threadIdx.x;   // over 4096*512/4
  const float c0 = coef[0], c1 = coef[1], c2 = coef[2], inv = coef[3];
  const float4 a  = ((const float4*)h0)[idx];
  const float4 s1 = ((const float4*)S1)[idx];
  const float4 s2 = ((const float4*)S2)[idx];
  const float4 s3 = ((const float4*)S3)[idx];
  ushort4 o;
  o.x = f2b((a.x + c0 * s1.x + c1 * s2.x + c2 * s3.x) * inv);
  o.y = f2b((a.y + c0 * s1.y + c1 * s2.y + c2 * s3.y) * inv);
  o.z = f2b((a.z + c0 * s1.z + c1 * s2.z + c2 * s3.z) * inv);
  o.w = f2b((a.w + c0 * s1.w + c1 * s2.w + c2 * s3.w) * inv);
  ((ushort4*)P)[idx] = o;
}

__global__ __launch_bounds__(256) void gather_emb(
    const int* __restrict__ tok, const float* __restrict__ emb, u16* __restrict__ Ag)
{
  const int idx = blockIdx.x * 256 + threadIdx.x;   // over 4096*128
  const int n = idx >> 7, c4 = idx & 127;
  const float4 v = ((const float4*)(emb + (size_t)tok[n] * 512))[c4];
  ushort4 o = { f2b(v.x), f2b(v.y), f2b(v.z), f2b(v.w) };
  ((ushort4*)(Ag + (size_t)n * 512))[c4] = o;
}

__global__ __launch_bounds__(256) void f32_to_bf16_vec(
    const float* __restrict__ src, u16* __restrict__ dst, int n4)
{
  const int idx = blockIdx.x * 256 + threadIdx.x;
  if (idx >= n4) return;
  const float4 v = ((const float4*)src)[idx];
  ushort4 o = { f2b(v.x), f2b(v.y), f2b(v.z), f2b(v.w) };
  ((ushort4*)dst)[idx] = o;
}

__global__ __launch_bounds__(256) void prep_wsum(
    const float* __restrict__ cf_w, u16* __restrict__ W)
{
  const int idx = blockIdx.x * 256 + threadIdx.x;   // over 512*512/4
  const float4 a = ((const float4*)cf_w)[idx];
  const float4 b = ((const float4*)(cf_w + 512 * 512))[idx];
  ushort4 o = { f2b(a.x + b.x), f2b(a.y + b.y), f2b(a.z + b.z), f2b(a.w + b.w) };
  ((ushort4*)W)[idx] = o;
}

__global__ void prep_cvec(const float* __restrict__ cf_b, const float* __restrict__ sib,
                          float* __restrict__ cvec, float* __restrict__ psum)
{
  const int t = threadIdx.x;   // 512 threads
  cvec[t] = cf_b[t] + cf_b[512 + t] + SIB_SCALE_F * (sib[t] + sib[512 + t]);
  if (t < 3) psum[t] = 0.f;
}

// ---------------------------------------------------------------------------
extern "C" void kernel_launch(void* const* d_in, const int* in_sizes, int n_in,
                              void* d_out, int out_size, void* d_ws, size_t ws_size,
                              hipStream_t stream) {
  const int*   tok    = (const int*)  d_in[0];
  const float* emb    = (const float*)d_in[1];
  const float* proj_w = (const float*)d_in[2];
  const float* proj_b = (const float*)d_in[3];
  const float* cf_w   = (const float*)d_in[4];
  const float* cf_b   = (const float*)d_in[5];
  const float* in_g   = (const float*)d_in[6];
  const float* in_b   = (const float*)d_in[7];
  const float* pde    = (const float*)d_in[8];
  const float* f1w    = (const float*)d_in[9];
  const float* f1b    = (const float*)d_in[10];
  const float* n1g    = (const float*)d_in[11];
  const float* n1b    = (const float*)d_in[12];
  const float* f2w    = (const float*)d_in[13];
  const float* f2bias = (const float*)d_in[14];
  const float* n2g    = (const float*)d_in[15];
  const float* n2b    = (const float*)d_in[16];
  const float* pow_w  = (const float*)d_in[17];
  const float* pow_b  = (const float*)d_in[18];
  const float* sib    = (const float*)d_in[19];
  const float* dep    = (const float*)d_in[20];
  const float* out_w  = (const float*)d_in[21];
  const float* out_b  = (const float*)d_in[22];
  float* out = (float*)d_out;

  char* ws = (char*)d_ws;
  size_t off = 0;
  auto alloc = [&](size_t bytes) -> void* {
    void* p = ws + off;
    off += (bytes + 255) & ~(size_t)255;
    return p;
  };
  u16*   outw_b  = (u16*)  alloc((size_t)32000 * 512 * 2);
  u16*   projw_b = (u16*)  alloc((size_t)512 * 512 * 2);
  u16*   wsum_b  = (u16*)  alloc((size_t)512 * 512 * 2);
  u16*   Ag      = (u16*)  alloc((size_t)4096 * 512 * 2);
  float* h0f     = (float*)alloc((size_t)4096 * 512 * 4);
  u16*   h0b     = (u16*)  alloc((size_t)4096 * 512 * 2);
  float* S1f     = (float*)alloc((size_t)4096 * 512 * 4);
  u16*   S1b     = (u16*)  alloc((size_t)4096 * 512 * 2);
  float* S2f     = (float*)alloc((size_t)4096 * 512 * 4);
  u16*   S2b     = (u16*)  alloc((size_t)4096 * 512 * 2);
  float* S3f     = (float*)alloc((size_t)4096 * 512 * 4);
  u16*   S3b     = (u16*)  alloc((size_t)4096 * 512 * 2);
  float* X       = (float*)alloc((size_t)4096 * 640 * 4);
  float* Y1      = (float*)alloc((size_t)4096 * 256 * 4);
  float* Y2      = (float*)alloc((size_t)4096 * 128 * 4);
  float* cvec    = (float*)alloc(512 * 4);
  float* psum    = (float*)alloc(256);
  float* coef    = (float*)alloc(256);
  u16*   poolb   = (u16*)  alloc((size_t)4096 * 512 * 2);

  // weight prep
  prep_cvec<<<1, 512, 0, stream>>>(cf_b, sib, cvec, psum);
  prep_wsum<<<256, 256, 0, stream>>>(cf_w, wsum_b);
  f32_to_bf16_vec<<<16000, 256, 0, stream>>>(out_w, outw_b, 4096000);
  f32_to_bf16_vec<<<256, 256, 0, stream>>>(proj_w, projw_b, 65536);
  gather_emb<<<2048, 256, 0, stream>>>(tok, emb, Ag);

  // h0 = emb[tok] @ proj_w^T + proj_b
  gemm_bf16_bt<<<dim3(32, 4), 256, 0, stream>>>(Ag, projw_b, proj_b, 1.f,
                                                h0f, h0b, 4096, 512, 512);
  // S_{l+1} = S_l @ (W_L+W_R)^T + 2^l * c
  gemm_bf16_bt<<<dim3(32, 4), 256, 0, stream>>>(h0b, wsum_b, cvec, 1.f,
                                                S1f, S1b, 4096, 512, 512);
  gemm_bf16_bt<<<dim3(32, 4), 256, 0, stream>>>(S1b, wsum_b, cvec, 2.f,
                                                S2f, S2b, 4096, 512, 512);
  gemm_bf16_bt<<<dim3(32, 4), 256, 0, stream>>>(S2b, wsum_b, cvec, 4.f,
                                                S3f, S3b, 4096, 512, 512);

  // policy (fp32): gates the aggregation coefficients
  const float* Sl[3] = {h0f, S1f, S2f};
  for (int l = 0; l < 3; ++l) {
    mean_ln_concat<<<1024, 256, 0, stream>>>(Sl[l], 1.f / (float)(1 << l),
                                             dep + 512 * l, pde + 128 * l,
                                             in_g, in_b, X);
    sgemm_bt<<<dim3(64, 4), 256, 0, stream>>>(X, f1w, f1b, Y1, 4096, 256, 640);
    ln_relu<256><<<1024, 256, 0, stream>>>(Y1, n1g, n1b);
    sgemm_bt<<<dim3(64, 2), 256, 0, stream>>>(Y1, f2w, f2bias, Y2, 4096, 128, 256);
    ln_relu<128><<<1024, 256, 0, stream>>>(Y2, n2g, n2b);
    policy_reduce<<<1024, 256, 0, stream>>>(Y2, pow_w, pow_b, psum + l);
  }
  finalize_coef<<<1, 1, 0, stream>>>(psum, coef);

  // pooled = (h0 + a1*S1 + a2*S2 + a3*S3) / cnt  -> bf16
  pool_to_bf16<<<2048, 256, 0, stream>>>(h0f, S1f, S2f, S3f, coef, poolb);

  // out = pooled @ out_w^T + out_b   (4096 x 32000 x 512)
  gemm_bf16_bt<<<dim3(32, 250), 256, 0, stream>>>(poolb, outw_b, out_b, 1.f,
                                                  out, nullptr, 4096, 32000, 512);
}

// Round 2
// 543.917 us; speedup vs baseline: 1.1378x; 1.1378x over previous
//
#include <hip/hip_runtime.h>

typedef unsigned short u16;
using bf16x8 = __attribute__((ext_vector_type(8))) short;
using f32x4  = __attribute__((ext_vector_type(4))) float;

#define SIB_SCALE_F 0.04419417382415922f   // 1/sqrt(512)

__device__ __forceinline__ u16 f2b(float f) {
  unsigned u = __builtin_bit_cast(unsigned, f);
  return (u16)((u + 0x7FFFu + ((u >> 16) & 1u)) >> 16);   // RNE
}

__device__ __forceinline__ float wred(float v) {
  #pragma unroll
  for (int m = 1; m < 64; m <<= 1) v += __shfl_xor(v, m);
  return v;
}

__device__ __forceinline__ void gload16(const void* g, void* l) {
  __builtin_amdgcn_global_load_lds(
      (const __attribute__((address_space(1))) unsigned int*)g,
      (__attribute__((address_space(3))) unsigned int*)l, 16, 0, 0);
}

// ---------------------------------------------------------------------------
// bf16 MFMA GEMM: C[M,N] = A[M,K] @ B[N,K]^T + bscale*bias[N]
// 128x128 tile, BK=32, 4 waves (2x2), 64x64 per wave (4x4 frags of 16x16).
// global_load_lds(16B) staging with XOR slot swizzle (pre-swizzled source).
// XCD-chunked block swizzle (grid total % 8 == 0 at all call sites).
// M%128==0, N%128==0, K%32==0 required.
// ---------------------------------------------------------------------------
__global__ __launch_bounds__(256) void gemm_bf16_bt(
    const u16* __restrict__ A, const u16* __restrict__ B,
    const float* __restrict__ bias, float bscale,
    float* __restrict__ C, u16* __restrict__ Cb,
    int M, int N, int K)
{
  __shared__ u16 ldsA[128 * 32];
  __shared__ u16 ldsB[128 * 32];
  const int t = threadIdx.x;
  const int w = t >> 6;
  const int lane = t & 63;
  const int wr = w >> 1, wc = w & 1;

  // XCD-chunked bijective swizzle: co-locate blocks sharing a B panel.
  const int nb = gridDim.x * gridDim.y;
  const int lid = blockIdx.y * gridDim.x + blockIdx.x;
  const int chunk = nb >> 3;
  const int nlid = (lid & 7) * chunk + (lid >> 3);
  const int bx = nlid % gridDim.x, by = nlid / gridDim.x;

  const int bm = bx * 128, bn = by * 128;
  const int r16 = lane & 15, ks = lane >> 4;
  const int srow = t >> 2, sslot = t & 3;

  f32x4 acc[4][4];
  #pragma unroll
  for (int m = 0; m < 4; ++m)
    #pragma unroll
    for (int n = 0; n < 4; ++n) {
      f32x4 z = {0.f, 0.f, 0.f, 0.f};
      acc[m][n] = z;
    }

  for (int k0 = 0; k0 < K; k0 += 32) {
    if (k0) __syncthreads();
    #pragma unroll
    for (int i = 0; i < 2; ++i) {
      const int row = srow + i * 64;
      const int sl = sslot ^ ((row >> 1) & 3);     // source pre-swizzle
      gload16(A + (size_t)(bm + row) * K + k0 + sl * 8,
              ldsA + (i * 2048 + w * 512));
      gload16(B + (size_t)(bn + row) * K + k0 + sl * 8,
              ldsB + (i * 2048 + w * 512));
    }
    __syncthreads();   // compiler drains vmcnt(0) before s_barrier

    bf16x8 af[4], bfr[4];
    #pragma unroll
    for (int m = 0; m < 4; ++m) {
      const int row = wr * 64 + m * 16 + r16;
      af[m] = *(const bf16x8*)(ldsA + row * 32 + ((ks ^ ((row >> 1) & 3)) << 3));
    }
    #pragma unroll
    for (int n = 0; n < 4; ++n) {
      const int row = wc * 64 + n * 16 + r16;
      bfr[n] = *(const bf16x8*)(ldsB + row * 32 + ((ks ^ ((row >> 1) & 3)) << 3));
    }
    #pragma unroll
    for (int m = 0; m < 4; ++m)
      #pragma unroll
      for (int n = 0; n < 4; ++n)
        acc[m][n] = __builtin_amdgcn_mfma_f32_16x16x32_bf16(af[m], bfr[n], acc[m][n], 0, 0, 0);
  }

  // epilogue: C/D layout col = lane&15, row = (lane>>4)*4 + reg
  #pragma unroll
  for (int m = 0; m < 4; ++m) {
    const int grow0 = bm + wr * 64 + m * 16 + ks * 4;
    #pragma unroll
    for (int n = 0; n < 4; ++n) {
      const int gcol = bn + wc * 64 + n * 16 + r16;
      const float bv = bias ? bias[gcol] * bscale : 0.f;
      #pragma unroll
      for (int r = 0; r < 4; ++r) {
        const float v = acc[m][n][r] + bv;
        const size_t idx = (size_t)(grow0 + r) * N + gcol;
        C[idx] = v;
        if (Cb) Cb[idx] = f2b(v);
      }
    }
  }
}

// ---------------------------------------------------------------------------
// fp32 SGEMM (policy path, numerically sensitive): C = A@B^T + bias
// 64x64 tile, BK=16, 256 threads, 4x4 per thread, float4 global staging.
// M%64==0, N%64==0, K%16==0.
// ---------------------------------------------------------------------------
__global__ __launch_bounds__(256) void sgemm_bt(
    const float* __restrict__ A, const float* __restrict__ B,
    const float* __restrict__ bias,
    float* __restrict__ C, int M, int N, int K)
{
  __shared__ float As[16][68];   // 68*4=272B row stride: 16B-aligned, pad kills conflicts
  __shared__ float Bs[16][68];
  const int t = threadIdx.x;
  const int tx = t & 15, ty = t >> 4;
  const int bm = blockIdx.x * 64, bn = blockIdx.y * 64;
  const int srow = t >> 2, skq = (t & 3) * 4;
  float acc[4][4] = {};
  for (int k0 = 0; k0 < K; k0 += 16) {
    if (k0) __syncthreads();
    {
      const float4 av = *(const float4*)&A[(size_t)(bm + srow) * K + k0 + skq];
      const float4 bv = *(const float4*)&B[(size_t)(bn + srow) * K + k0 + skq];
      As[skq + 0][srow] = av.x; As[skq + 1][srow] = av.y;
      As[skq + 2][srow] = av.z; As[skq + 3][srow] = av.w;
      Bs[skq + 0][srow] = bv.x; Bs[skq + 1][srow] = bv.y;
      Bs[skq + 2][srow] = bv.z; Bs[skq + 3][srow] = bv.w;
    }
    __syncthreads();
    #pragma unroll
    for (int kk = 0; kk < 16; ++kk) {
      const float4 av = *(const float4*)&As[kk][ty * 4];
      const float4 bv = *(const float4*)&Bs[kk][tx * 4];
      const float ar[4] = {av.x, av.y, av.z, av.w};
      const float br[4] = {bv.x, bv.y, bv.z, bv.w};
      #pragma unroll
      for (int i = 0; i < 4; ++i)
        #pragma unroll
        for (int j = 0; j < 4; ++j)
          acc[i][j] += ar[i] * br[j];
    }
  }
  #pragma unroll
  for (int i = 0; i < 4; ++i) {
    const int grow = bm + ty * 4 + i;
    #pragma unroll
    for (int j = 0; j < 4; ++j) {
      const int gcol = bn + tx * 4 + j;
      C[(size_t)grow * N + gcol] = acc[i][j] + bias[gcol];
    }
  }
}

// ---------------------------------------------------------------------------
// batched policy input over 3 levels: row g = l*4096+n
// X[g, 0:512] = LN(S_l[n]/2^l + 0.01*dep_l)*g+b ; X[g,512:640]=pde_l
// wave per row, 4 rows/block, grid 3072
// ---------------------------------------------------------------------------
__global__ __launch_bounds__(256) void mean_ln_concat_b(
    const float* __restrict__ S0, const float* __restrict__ S1,
    const float* __restrict__ S2,
    const float* __restrict__ dep, const float* __restrict__ pde,
    const float* __restrict__ g, const float* __restrict__ b,
    float* __restrict__ X)
{
  const int wid = threadIdx.x >> 6, lane = threadIdx.x & 63;
  const int gr = blockIdx.x * 4 + wid;          // 0..12287
  const int l = gr >> 12, n = gr & 4095;
  const float* Sr = (l == 0 ? S0 : l == 1 ? S1 : S2) + (size_t)n * 512;
  const float invM = (l == 0 ? 1.f : l == 1 ? 0.5f : 0.25f);
  const float* depl = dep + 512 * l;
  const float* pdel = pde + 128 * l;
  const int c0 = lane * 8;
  float x[8];
  float s = 0.f, sq = 0.f;
  #pragma unroll
  for (int i = 0; i < 8; ++i) {
    const float v = Sr[c0 + i] * invM + 0.01f * depl[c0 + i];
    x[i] = v; s += v; sq += v * v;
  }
  s = wred(s); sq = wred(sq);
  const float mean = s * (1.f / 512.f);
  const float var = sq * (1.f / 512.f) - mean * mean;
  const float rs = rsqrtf(var + 1e-5f);
  float* Xr = X + (size_t)gr * 640;
  #pragma unroll
  for (int i = 0; i < 8; ++i) {
    const int c = c0 + i;
    Xr[c] = (x[i] - mean) * rs * g[c] + b[c];
  }
  Xr[512 + lane * 2]     = pdel[lane * 2];
  Xr[512 + lane * 2 + 1] = pdel[lane * 2 + 1];
}

template <int C>
__global__ __launch_bounds__(256) void ln_relu(
    float* __restrict__ X, const float* __restrict__ g, const float* __restrict__ b)
{
  constexpr int E = C / 64;
  const int wid = threadIdx.x >> 6, lane = threadIdx.x & 63;
  const int n = blockIdx.x * 4 + wid;
  float* Xr = X + (size_t)n * C;
  float x[E];
  float s = 0.f, sq = 0.f;
  #pragma unroll
  for (int i = 0; i < E; ++i) {
    x[i] = Xr[lane * E + i]; s += x[i]; sq += x[i] * x[i];
  }
  s = wred(s); sq = wred(sq);
  const float mean = s * (1.f / (float)C);
  const float var = sq * (1.f / (float)C) - mean * mean;
  const float rs = rsqrtf(var + 1e-5f);
  #pragma unroll
  for (int i = 0; i < E; ++i) {
    const int c = lane * E + i;
    Xr[c] = fmaxf((x[i] - mean) * rs * g[c] + b[c], 0.f);
  }
}

// batched over 3 levels: row g = l*4096+n -> atomicAdd(psum[l], clip(sigmoid))
__global__ __launch_bounds__(256) void policy_reduce_b(
    const float* __restrict__ Y2, const float* __restrict__ pw,
    const float* __restrict__ pb, float* __restrict__ psum)
{
  __shared__ float part[4];
  const int wid = threadIdx.x >> 6, lane = threadIdx.x & 63;
  const int gr = blockIdx.x * 4 + wid;
  const float* r = Y2 + (size_t)gr * 128;
  float z = r[lane * 2] * pw[lane * 2] + r[lane * 2 + 1] * pw[lane * 2 + 1];
  z = wred(z);
  if (lane == 0) {
    const float p = 1.f / (1.f + expf(-(z + pb[0])));
    part[wid] = fminf(fmaxf(p, 1e-7f), 1.f - 1e-7f);
  }
  __syncthreads();
  if (threadIdx.x == 0) {
    // all 4 rows of this block are in the same level (4096 % 4 == 0)
    atomicAdd(psum + (gr >> 12), part[0] + part[1] + part[2] + part[3]);
  }
}

__global__ void finalize_coef(const float* __restrict__ psum, float* __restrict__ coef)
{
  float alive = 1.f, cnt = 1.f;
  #pragma unroll
  for (int l = 0; l < 3; ++l) {
    const float pm = psum[l] * (1.f / 4096.f);
    if (!(pm >= 0.5f)) alive = 0.f;
    coef[l] = alive;
    cnt += alive * (float)(2 << l);
  }
  coef[3] = 1.f / fmaxf(cnt, 1e-8f);
}

__global__ __launch_bounds__(256) void pool_to_bf16(
    const float* __restrict__ h0, const float* __restrict__ S1,
    const float* __restrict__ S2, const float* __restrict__ S3,
    const float* __restrict__ coef, u16* __restrict__ P)
{
  const int idx = blockIdx.x * 256 + threadIdx.x;   // over 4096*512/4
  const float c0 = coef[0], c1 = coef[1], c2 = coef[2], inv = coef[3];
  const float4 a  = ((const float4*)h0)[idx];
  const float4 s1 = ((const float4*)S1)[idx];
  const float4 s2 = ((const float4*)S2)[idx];
  const float4 s3 = ((const float4*)S3)[idx];
  ushort4 o;
  o.x = f2b((a.x + c0 * s1.x + c1 * s2.x + c2 * s3.x) * inv);
  o.y = f2b((a.y + c0 * s1.y + c1 * s2.y + c2 * s3.y) * inv);
  o.z = f2b((a.z + c0 * s1.z + c1 * s2.z + c2 * s3.z) * inv);
  o.w = f2b((a.w + c0 * s1.w + c1 * s2.w + c2 * s3.w) * inv);
  ((ushort4*)P)[idx] = o;
}

__global__ __launch_bounds__(256) void gather_emb(
    const int* __restrict__ tok, const float* __restrict__ emb, u16* __restrict__ Ag)
{
  const int idx = blockIdx.x * 256 + threadIdx.x;   // over 4096*128
  const int n = idx >> 7, c4 = idx & 127;
  const float4 v = ((const float4*)(emb + (size_t)tok[n] * 512))[c4];
  ushort4 o = { f2b(v.x), f2b(v.y), f2b(v.z), f2b(v.w) };
  ((ushort4*)(Ag + (size_t)n * 512))[c4] = o;
}

__global__ __launch_bounds__(256) void f32_to_bf16_vec(
    const float* __restrict__ src, u16* __restrict__ dst, int n4)
{
  const int idx = blockIdx.x * 256 + threadIdx.x;
  if (idx >= n4) return;
  const float4 v = ((const float4*)src)[idx];
  ushort4 o = { f2b(v.x), f2b(v.y), f2b(v.z), f2b(v.w) };
  ((ushort4*)dst)[idx] = o;
}

__global__ __launch_bounds__(256) void prep_wsum(
    const float* __restrict__ cf_w, u16* __restrict__ W)
{
  const int idx = blockIdx.x * 256 + threadIdx.x;   // over 512*512/4
  const float4 a = ((const float4*)cf_w)[idx];
  const float4 b = ((const float4*)(cf_w + 512 * 512))[idx];
  ushort4 o = { f2b(a.x + b.x), f2b(a.y + b.y), f2b(a.z + b.z), f2b(a.w + b.w) };
  ((ushort4*)W)[idx] = o;
}

__global__ void prep_cvec(const float* __restrict__ cf_b, const float* __restrict__ sib,
                          float* __restrict__ cvec, float* __restrict__ psum)
{
  const int t = threadIdx.x;   // 512 threads
  cvec[t] = cf_b[t] + cf_b[512 + t] + SIB_SCALE_F * (sib[t] + sib[512 + t]);
  if (t < 3) psum[t] = 0.f;
}

// ---------------------------------------------------------------------------
extern "C" void kernel_launch(void* const* d_in, const int* in_sizes, int n_in,
                              void* d_out, int out_size, void* d_ws, size_t ws_size,
                              hipStream_t stream) {
  const int*   tok    = (const int*)  d_in[0];
  const float* emb    = (const float*)d_in[1];
  const float* proj_w = (const float*)d_in[2];
  const float* proj_b = (const float*)d_in[3];
  const float* cf_w   = (const float*)d_in[4];
  const float* cf_b   = (const float*)d_in[5];
  const float* in_g   = (const float*)d_in[6];
  const float* in_b   = (const float*)d_in[7];
  const float* pde    = (const float*)d_in[8];
  const float* f1w    = (const float*)d_in[9];
  const float* f1b    = (const float*)d_in[10];
  const float* n1g    = (const float*)d_in[11];
  const float* n1b    = (const float*)d_in[12];
  const float* f2w    = (const float*)d_in[13];
  const float* f2bias = (const float*)d_in[14];
  const float* n2g    = (const float*)d_in[15];
  const float* n2b    = (const float*)d_in[16];
  const float* pow_w  = (const float*)d_in[17];
  const float* pow_b  = (const float*)d_in[18];
  const float* sib    = (const float*)d_in[19];
  const float* dep    = (const float*)d_in[20];
  const float* out_w  = (const float*)d_in[21];
  const float* out_b  = (const float*)d_in[22];
  float* out = (float*)d_out;

  char* ws = (char*)d_ws;
  size_t off = 0;
  auto alloc = [&](size_t bytes) -> void* {
    void* p = ws + off;
    off += (bytes + 255) & ~(size_t)255;
    return p;
  };
  u16*   outw_b  = (u16*)  alloc((size_t)32000 * 512 * 2);
  u16*   projw_b = (u16*)  alloc((size_t)512 * 512 * 2);
  u16*   wsum_b  = (u16*)  alloc((size_t)512 * 512 * 2);
  u16*   Ag      = (u16*)  alloc((size_t)4096 * 512 * 2);
  float* h0f     = (float*)alloc((size_t)4096 * 512 * 4);
  u16*   h0b     = (u16*)  alloc((size_t)4096 * 512 * 2);
  float* S1f     = (float*)alloc((size_t)4096 * 512 * 4);
  u16*   S1b     = (u16*)  alloc((size_t)4096 * 512 * 2);
  float* S2f     = (float*)alloc((size_t)4096 * 512 * 4);
  u16*   S2b     = (u16*)  alloc((size_t)4096 * 512 * 2);
  float* S3f     = (float*)alloc((size_t)4096 * 512 * 4);
  u16*   S3b     = (u16*)  alloc((size_t)4096 * 512 * 2);
  float* X       = (float*)alloc((size_t)12288 * 640 * 4);
  float* Y1      = (float*)alloc((size_t)12288 * 256 * 4);
  float* Y2      = (float*)alloc((size_t)12288 * 128 * 4);
  float* cvec    = (float*)alloc(512 * 4);
  float* psum    = (float*)alloc(256);
  float* coef    = (float*)alloc(256);
  u16*   poolb   = (u16*)  alloc((size_t)4096 * 512 * 2);

  // weight prep
  prep_cvec<<<1, 512, 0, stream>>>(cf_b, sib, cvec, psum);
  prep_wsum<<<256, 256, 0, stream>>>(cf_w, wsum_b);
  f32_to_bf16_vec<<<16000, 256, 0, stream>>>(out_w, outw_b, 4096000);
  f32_to_bf16_vec<<<256, 256, 0, stream>>>(proj_w, projw_b, 65536);
  gather_emb<<<2048, 256, 0, stream>>>(tok, emb, Ag);

  // h0 = emb[tok] @ proj_w^T + proj_b
  gemm_bf16_bt<<<dim3(32, 4), 256, 0, stream>>>(Ag, projw_b, proj_b, 1.f,
                                                h0f, h0b, 4096, 512, 512);
  // S_{l+1} = S_l @ (W_L+W_R)^T + 2^l * c
  gemm_bf16_bt<<<dim3(32, 4), 256, 0, stream>>>(h0b, wsum_b, cvec, 1.f,
                                                S1f, S1b, 4096, 512, 512);
  gemm_bf16_bt<<<dim3(32, 4), 256, 0, stream>>>(S1b, wsum_b, cvec, 2.f,
                                                S2f, S2b, 4096, 512, 512);
  gemm_bf16_bt<<<dim3(32, 4), 256, 0, stream>>>(S2b, wsum_b, cvec, 4.f,
                                                S3f, S3b, 4096, 512, 512);

  // policy (fp32), all 3 levels batched as M=12288
  mean_ln_concat_b<<<3072, 256, 0, stream>>>(h0f, S1f, S2f, dep, pde,
                                             in_g, in_b, X);
  sgemm_bt<<<dim3(192, 4), 256, 0, stream>>>(X, f1w, f1b, Y1, 12288, 256, 640);
  ln_relu<256><<<3072, 256, 0, stream>>>(Y1, n1g, n1b);
  sgemm_bt<<<dim3(192, 2), 256, 0, stream>>>(Y1, f2w, f2bias, Y2, 12288, 128, 256);
  ln_relu<128><<<3072, 256, 0, stream>>>(Y2, n2g, n2b);
  policy_reduce_b<<<3072, 256, 0, stream>>>(Y2, pow_w, pow_b, psum);
  finalize_coef<<<1, 1, 0, stream>>>(psum, coef);

  // pooled = (h0 + a1*S1 + a2*S2 + a3*S3) / cnt  -> bf16
  pool_to_bf16<<<2048, 256, 0, stream>>>(h0f, S1f, S2f, S3f, coef, poolb);

  // out = pooled @ out_w^T + out_b   (4096 x 32000 x 512)
  gemm_bf16_bt<<<dim3(32, 250), 256, 0, stream>>>(poolb, outw_b, out_b, 1.f,
                                                  out, nullptr, 4096, 32000, 512);
}

// Round 3
// 513.509 us; speedup vs baseline: 1.2051x; 1.0592x over previous
//
#include <hip/hip_runtime.h>

typedef unsigned short u16;
using bf16x8 = __attribute__((ext_vector_type(8))) short;
using f32x4  = __attribute__((ext_vector_type(4))) float;

#define SIB_SCALE_F 0.04419417382415922f   // 1/sqrt(512)

__device__ __forceinline__ u16 f2b(float f) {
  unsigned u = __builtin_bit_cast(unsigned, f);
  return (u16)((u + 0x7FFFu + ((u >> 16) & 1u)) >> 16);   // RNE
}

__device__ __forceinline__ float wred(float v) {
  #pragma unroll
  for (int m = 1; m < 64; m <<= 1) v += __shfl_xor(v, m);
  return v;
}

__device__ __forceinline__ void gload16(const void* g, void* l) {
  __builtin_amdgcn_global_load_lds(
      (const __attribute__((address_space(1))) unsigned int*)g,
      (__attribute__((address_space(3))) unsigned int*)l, 16, 0, 0);
}

// ---------------------------------------------------------------------------
// 256x256 bf16 MFMA GEMM with counted-vmcnt double-buffer pipeline.
// C[M,N] = A[M,K]@B[N,K]^T + bias[N].  BK=64, 512 thr (8 waves, 2M x 4N),
// per-wave 128x64 (8x4 frags).  LDS 128 KiB: A[2][256][64], B[2][256][64],
// XOR slot swizzle (slot ^= row&7) -> conflict-free ds_read_b128; staged via
// global_load_lds(16B) with pre-swizzled per-lane SOURCE (LDS dest linear).
// Main loop: raw s_barrier + s_waitcnt vmcnt(8) (one K-tile always in
// flight), stage(t+2) overlapped with second MFMA half, setprio around MFMA.
// M%256==0, N%256==0, K%64==0, K>=128.
// ---------------------------------------------------------------------------
__global__ __launch_bounds__(512) void gemm256_bt(
    const u16* __restrict__ A, const u16* __restrict__ B,
    const float* __restrict__ bias,
    float* __restrict__ C, int M, int N, int K)
{
  __shared__ u16 lds[65536];   // A: [0,32768) ; B: [32768,65536)  (u16 units)
  const int t = threadIdx.x, w = t >> 6, lane = t & 63;
  const int wm = w >> 2, wn = w & 3;
  const int r16 = lane & 15, ks = lane >> 4;

  // XCD-chunked bijective swizzle (grid % 8 == 0), bx fastest = B-panel reuse
  const int nb = gridDim.x * gridDim.y;
  const int lid = blockIdx.y * gridDim.x + blockIdx.x;
  const int chunk = nb >> 3;
  const int nlid = (lid & 7) * chunk + (lid >> 3);
  const int bm = (nlid % gridDim.x) * 256;
  const int bn = (nlid / gridDim.x) * 256;

  const int NT = K >> 6;

  auto stage = [&](const u16* __restrict__ G, int row0, int kt, u16* base) {
    const int k0 = kt << 6;
    u16* dst = base + (kt & 1) * 16384;
    #pragma unroll
    for (int i = 0; i < 4; ++i) {
      const int rb = (w * 4 + i) * 8;          // 8-row chunk per wave-call
      const int r  = rb + (lane >> 3);
      const int s  = (lane & 7) ^ (r & 7);     // pre-swizzled source slot
      gload16(G + (size_t)(row0 + r) * K + k0 + s * 8, dst + rb * 64);
    }
  };

  f32x4 acc[8][4];
  #pragma unroll
  for (int m = 0; m < 8; ++m)
    #pragma unroll
    for (int n = 0; n < 4; ++n) {
      f32x4 z = {0.f, 0.f, 0.f, 0.f};
      acc[m][n] = z;
    }

  // prologue: two K-tiles in flight
  stage(A, bm, 0, lds); stage(B, bn, 0, lds + 32768);
  stage(A, bm, 1, lds); stage(B, bn, 1, lds + 32768);

  for (int kt = 0; kt < NT; ++kt) {
    // tile kt fully landed; tile kt+1 (8 loads) may remain in flight
    if (kt < NT - 1) asm volatile("s_waitcnt vmcnt(8)" ::: "memory");
    else             asm volatile("s_waitcnt vmcnt(0)" ::: "memory");
    __builtin_amdgcn_sched_barrier(0);
    __builtin_amdgcn_s_barrier();              // all waves' tile-kt loads done

    const u16* Ab = lds + (kt & 1) * 16384;
    const u16* Bb = lds + 32768 + (kt & 1) * 16384;

    bf16x8 af[8], bf4[4];
    // ---- ksub 0 (k 0..31 of this K-tile) ----
    #pragma unroll
    for (int m = 0; m < 8; ++m) {
      const int row = wm * 128 + m * 16 + r16;
      af[m] = *(const bf16x8*)(Ab + row * 64 + ((ks ^ (row & 7)) << 3));
    }
    #pragma unroll
    for (int n = 0; n < 4; ++n) {
      const int row = wn * 64 + n * 16 + r16;
      bf4[n] = *(const bf16x8*)(Bb + row * 64 + ((ks ^ (row & 7)) << 3));
    }
    asm volatile("s_waitcnt lgkmcnt(0)" ::: "memory");
    __builtin_amdgcn_sched_barrier(0);
    __builtin_amdgcn_s_setprio(1);
    #pragma unroll
    for (int m = 0; m < 8; ++m)
      #pragma unroll
      for (int n = 0; n < 4; ++n)
        acc[m][n] = __builtin_amdgcn_mfma_f32_16x16x32_bf16(af[m], bf4[n], acc[m][n], 0, 0, 0);
    __builtin_amdgcn_s_setprio(0);

    // ---- ksub 1 reads (k 32..63) ----
    #pragma unroll
    for (int m = 0; m < 8; ++m) {
      const int row = wm * 128 + m * 16 + r16;
      af[m] = *(const bf16x8*)(Ab + row * 64 + (((4 + ks) ^ (row & 7)) << 3));
    }
    #pragma unroll
    for (int n = 0; n < 4; ++n) {
      const int row = wn * 64 + n * 16 + r16;
      bf4[n] = *(const bf16x8*)(Bb + row * 64 + (((4 + ks) ^ (row & 7)) << 3));
    }
    asm volatile("s_waitcnt lgkmcnt(0)" ::: "memory");
    __builtin_amdgcn_sched_barrier(0);
    __builtin_amdgcn_s_barrier();              // everyone's reads of buf done

    if (kt + 2 < NT) {                         // overwrite buf[kt&1] for kt+2
      stage(A, bm, kt + 2, lds);
      stage(B, bn, kt + 2, lds + 32768);
    }

    __builtin_amdgcn_s_setprio(1);
    #pragma unroll
    for (int m = 0; m < 8; ++m)
      #pragma unroll
      for (int n = 0; n < 4; ++n)
        acc[m][n] = __builtin_amdgcn_mfma_f32_16x16x32_bf16(af[m], bf4[n], acc[m][n], 0, 0, 0);
    __builtin_amdgcn_s_setprio(0);
  }

  // epilogue: C/D layout col = lane&15, row = (lane>>4)*4 + reg
  #pragma unroll
  for (int n = 0; n < 4; ++n) {
    const int gcol = bn + wn * 64 + n * 16 + r16;
    const float bv = bias[gcol];
    #pragma unroll
    for (int m = 0; m < 8; ++m) {
      const int grow0 = bm + wm * 128 + m * 16 + ks * 4;
      #pragma unroll
      for (int r = 0; r < 4; ++r)
        C[(size_t)(grow0 + r) * N + gcol] = acc[m][n][r] + bv;
    }
  }
}

// ---------------------------------------------------------------------------
// bf16 MFMA GEMM (chain path): C[M,N] = A@B^T + bscale*bias, 128x128, BK=32.
// ---------------------------------------------------------------------------
__global__ __launch_bounds__(256) void gemm_bf16_bt(
    const u16* __restrict__ A, const u16* __restrict__ B,
    const float* __restrict__ bias, float bscale,
    float* __restrict__ C, u16* __restrict__ Cb,
    int M, int N, int K)
{
  __shared__ u16 ldsA[128 * 32];
  __shared__ u16 ldsB[128 * 32];
  const int t = threadIdx.x;
  const int w = t >> 6;
  const int lane = t & 63;
  const int wr = w >> 1, wc = w & 1;

  const int nb = gridDim.x * gridDim.y;
  const int lid = blockIdx.y * gridDim.x + blockIdx.x;
  const int chunk = nb >> 3;
  const int nlid = (lid & 7) * chunk + (lid >> 3);
  const int bx = nlid % gridDim.x, by = nlid / gridDim.x;

  const int bm = bx * 128, bn = by * 128;
  const int r16 = lane & 15, ks = lane >> 4;
  const int srow = t >> 2, sslot = t & 3;

  f32x4 acc[4][4];
  #pragma unroll
  for (int m = 0; m < 4; ++m)
    #pragma unroll
    for (int n = 0; n < 4; ++n) {
      f32x4 z = {0.f, 0.f, 0.f, 0.f};
      acc[m][n] = z;
    }

  for (int k0 = 0; k0 < K; k0 += 32) {
    if (k0) __syncthreads();
    #pragma unroll
    for (int i = 0; i < 2; ++i) {
      const int row = srow + i * 64;
      const int sl = sslot ^ ((row >> 1) & 3);
      gload16(A + (size_t)(bm + row) * K + k0 + sl * 8,
              ldsA + (i * 2048 + w * 512));
      gload16(B + (size_t)(bn + row) * K + k0 + sl * 8,
              ldsB + (i * 2048 + w * 512));
    }
    __syncthreads();

    bf16x8 af[4], bfr[4];
    #pragma unroll
    for (int m = 0; m < 4; ++m) {
      const int row = wr * 64 + m * 16 + r16;
      af[m] = *(const bf16x8*)(ldsA + row * 32 + ((ks ^ ((row >> 1) & 3)) << 3));
    }
    #pragma unroll
    for (int n = 0; n < 4; ++n) {
      const int row = wc * 64 + n * 16 + r16;
      bfr[n] = *(const bf16x8*)(ldsB + row * 32 + ((ks ^ ((row >> 1) & 3)) << 3));
    }
    #pragma unroll
    for (int m = 0; m < 4; ++m)
      #pragma unroll
      for (int n = 0; n < 4; ++n)
        acc[m][n] = __builtin_amdgcn_mfma_f32_16x16x32_bf16(af[m], bfr[n], acc[m][n], 0, 0, 0);
  }

  #pragma unroll
  for (int m = 0; m < 4; ++m) {
    const int grow0 = bm + wr * 64 + m * 16 + ks * 4;
    #pragma unroll
    for (int n = 0; n < 4; ++n) {
      const int gcol = bn + wc * 64 + n * 16 + r16;
      const float bv = bias ? bias[gcol] * bscale : 0.f;
      #pragma unroll
      for (int r = 0; r < 4; ++r) {
        const float v = acc[m][n][r] + bv;
        const size_t idx = (size_t)(grow0 + r) * N + gcol;
        C[idx] = v;
        if (Cb) Cb[idx] = f2b(v);
      }
    }
  }
}

// ---------------------------------------------------------------------------
// fp32 SGEMM (policy path): C = A@B^T + bias[level-select]
// 64x64 tile, BK=16, 256 threads, 4x4/thread, float4 staging.
// lda/ldb are row strides.  bias_eff = bias + (bm>>12)*bias_lvl.
// ---------------------------------------------------------------------------
__global__ __launch_bounds__(256) void sgemm_bt(
    const float* __restrict__ A, int lda,
    const float* __restrict__ B, int ldb,
    const float* __restrict__ bias, int bias_lvl,
    float* __restrict__ C, int M, int N, int K)
{
  __shared__ float As[16][68];
  __shared__ float Bs[16][68];
  const int t = threadIdx.x;
  const int tx = t & 15, ty = t >> 4;
  const int bm = blockIdx.x * 64, bn = blockIdx.y * 64;
  const float* be = bias + (size_t)(bm >> 12) * bias_lvl;
  const int srow = t >> 2, skq = (t & 3) * 4;
  float acc[4][4] = {};
  for (int k0 = 0; k0 < K; k0 += 16) {
    if (k0) __syncthreads();
    {
      const float4 av = *(const float4*)&A[(size_t)(bm + srow) * lda + k0 + skq];
      const float4 bv = *(const float4*)&B[(size_t)(bn + srow) * ldb + k0 + skq];
      As[skq + 0][srow] = av.x; As[skq + 1][srow] = av.y;
      As[skq + 2][srow] = av.z; As[skq + 3][srow] = av.w;
      Bs[skq + 0][srow] = bv.x; Bs[skq + 1][srow] = bv.y;
      Bs[skq + 2][srow] = bv.z; Bs[skq + 3][srow] = bv.w;
    }
    __syncthreads();
    #pragma unroll
    for (int kk = 0; kk < 16; ++kk) {
      const float4 av = *(const float4*)&As[kk][ty * 4];
      const float4 bv = *(const float4*)&Bs[kk][tx * 4];
      const float ar[4] = {av.x, av.y, av.z, av.w};
      const float br[4] = {bv.x, bv.y, bv.z, bv.w};
      #pragma unroll
      for (int i = 0; i < 4; ++i)
        #pragma unroll
        for (int j = 0; j < 4; ++j)
          acc[i][j] += ar[i] * br[j];
    }
  }
  #pragma unroll
  for (int i = 0; i < 4; ++i) {
    const int grow = bm + ty * 4 + i;
    #pragma unroll
    for (int j = 0; j < 4; ++j) {
      const int gcol = bn + tx * 4 + j;
      C[(size_t)grow * N + gcol] = acc[i][j] + be[gcol];
    }
  }
}

// y1bias[l][j] = f1b[j] + sum_k f1w[j][512+k] * pde[l][k]   (3 x 256)
__global__ void prep_y1bias(const float* __restrict__ f1w, const float* __restrict__ f1b,
                            const float* __restrict__ pde, float* __restrict__ y1bias)
{
  const int l = blockIdx.x, j = threadIdx.x;
  const float* wrow = f1w + (size_t)j * 640 + 512;
  const float* p = pde + l * 128;
  float s = f1b[j];
  #pragma unroll 4
  for (int k = 0; k < 128; ++k) s += wrow[k] * p[k];
  y1bias[l * 256 + j] = s;
}

// ---------------------------------------------------------------------------
// batched policy input over 3 levels: row g = l*4096+n
// X[g, 0:512] = LN(S_l[n]/2^l + 0.01*dep_l)*g+b   (stride 512; pde folded out)
// ---------------------------------------------------------------------------
__global__ __launch_bounds__(256) void mean_ln_concat_b(
    const float* __restrict__ S0, const float* __restrict__ S1,
    const float* __restrict__ S2,
    const float* __restrict__ dep,
    const float* __restrict__ g, const float* __restrict__ b,
    float* __restrict__ X)
{
  const int wid = threadIdx.x >> 6, lane = threadIdx.x & 63;
  const int gr = blockIdx.x * 4 + wid;          // 0..12287
  const int l = gr >> 12, n = gr & 4095;
  const float* Sr = (l == 0 ? S0 : l == 1 ? S1 : S2) + (size_t)n * 512;
  const float invM = (l == 0 ? 1.f : l == 1 ? 0.5f : 0.25f);
  const float* depl = dep + 512 * l;
  const int c0 = lane * 8;
  float x[8];
  float s = 0.f, sq = 0.f;
  #pragma unroll
  for (int i = 0; i < 8; ++i) {
    const float v = Sr[c0 + i] * invM + 0.01f * depl[c0 + i];
    x[i] = v; s += v; sq += v * v;
  }
  s = wred(s); sq = wred(sq);
  const float mean = s * (1.f / 512.f);
  const float var = sq * (1.f / 512.f) - mean * mean;
  const float rs = rsqrtf(var + 1e-5f);
  float* Xr = X + (size_t)gr * 512;
  #pragma unroll
  for (int i = 0; i < 8; ++i) {
    const int c = c0 + i;
    Xr[c] = (x[i] - mean) * rs * g[c] + b[c];
  }
}

template <int C>
__global__ __launch_bounds__(256) void ln_relu(
    float* __restrict__ X, const float* __restrict__ g, const float* __restrict__ b)
{
  constexpr int E = C / 64;
  const int wid = threadIdx.x >> 6, lane = threadIdx.x & 63;
  const int n = blockIdx.x * 4 + wid;
  float* Xr = X + (size_t)n * C;
  float x[E];
  float s = 0.f, sq = 0.f;
  #pragma unroll
  for (int i = 0; i < E; ++i) {
    x[i] = Xr[lane * E + i]; s += x[i]; sq += x[i] * x[i];
  }
  s = wred(s); sq = wred(sq);
  const float mean = s * (1.f / (float)C);
  const float var = sq * (1.f / (float)C) - mean * mean;
  const float rs = rsqrtf(var + 1e-5f);
  #pragma unroll
  for (int i = 0; i < E; ++i) {
    const int c = lane * E + i;
    Xr[c] = fmaxf((x[i] - mean) * rs * g[c] + b[c], 0.f);
  }
}

__global__ __launch_bounds__(256) void policy_reduce_b(
    const float* __restrict__ Y2, const float* __restrict__ pw,
    const float* __restrict__ pb, float* __restrict__ psum)
{
  __shared__ float part[4];
  const int wid = threadIdx.x >> 6, lane = threadIdx.x & 63;
  const int gr = blockIdx.x * 4 + wid;
  const float* r = Y2 + (size_t)gr * 128;
  float z = r[lane * 2] * pw[lane * 2] + r[lane * 2 + 1] * pw[lane * 2 + 1];
  z = wred(z);
  if (lane == 0) {
    const float p = 1.f / (1.f + expf(-(z + pb[0])));
    part[wid] = fminf(fmaxf(p, 1e-7f), 1.f - 1e-7f);
  }
  __syncthreads();
  if (threadIdx.x == 0)
    atomicAdd(psum + (gr >> 12), part[0] + part[1] + part[2] + part[3]);
}

__global__ void finalize_coef(const float* __restrict__ psum, float* __restrict__ coef)
{
  float alive = 1.f, cnt = 1.f;
  #pragma unroll
  for (int l = 0; l < 3; ++l) {
    const float pm = psum[l] * (1.f / 4096.f);
    if (!(pm >= 0.5f)) alive = 0.f;
    coef[l] = alive;
    cnt += alive * (float)(2 << l);
  }
  coef[3] = 1.f / fmaxf(cnt, 1e-8f);
}

__global__ __launch_bounds__(256) void pool_to_bf16(
    const float* __restrict__ h0, const float* __restrict__ S1,
    const float* __restrict__ S2, const float* __restrict__ S3,
    const float* __restrict__ coef, u16* __restrict__ P)
{
  const int idx = blockIdx.x * 256 + threadIdx.x;   // over 4096*512/4
  const float c0 = coef[0], c1 = coef[1], c2 = coef[2], inv = coef[3];
  const float4 a  = ((const float4*)h0)[idx];
  const float4 s1 = ((const float4*)S1)[idx];
  const float4 s2 = ((const float4*)S2)[idx];
  const float4 s3 = ((const float4*)S3)[idx];
  ushort4 o;
  o.x = f2b((a.x + c0 * s1.x + c1 * s2.x + c2 * s3.x) * inv);
  o.y = f2b((a.y + c0 * s1.y + c1 * s2.y + c2 * s3.y) * inv);
  o.z = f2b((a.z + c0 * s1.z + c1 * s2.z + c2 * s3.z) * inv);
  o.w = f2b((a.w + c0 * s1.w + c1 * s2.w + c2 * s3.w) * inv);
  ((ushort4*)P)[idx] = o;
}

__global__ __launch_bounds__(256) void gather_emb(
    const int* __restrict__ tok, const float* __restrict__ emb, u16* __restrict__ Ag)
{
  const int idx = blockIdx.x * 256 + threadIdx.x;   // over 4096*128
  const int n = idx >> 7, c4 = idx & 127;
  const float4 v = ((const float4*)(emb + (size_t)tok[n] * 512))[c4];
  ushort4 o = { f2b(v.x), f2b(v.y), f2b(v.z), f2b(v.w) };
  ((ushort4*)(Ag + (size_t)n * 512))[c4] = o;
}

__global__ __launch_bounds__(256) void f32_to_bf16_vec(
    const float* __restrict__ src, u16* __restrict__ dst, int n4)
{
  const int idx = blockIdx.x * 256 + threadIdx.x;
  if (idx >= n4) return;
  const float4 v = ((const float4*)src)[idx];
  ushort4 o = { f2b(v.x), f2b(v.y), f2b(v.z), f2b(v.w) };
  ((ushort4*)dst)[idx] = o;
}

__global__ __launch_bounds__(256) void prep_wsum(
    const float* __restrict__ cf_w, u16* __restrict__ W)
{
  const int idx = blockIdx.x * 256 + threadIdx.x;   // over 512*512/4
  const float4 a = ((const float4*)cf_w)[idx];
  const float4 b = ((const float4*)(cf_w + 512 * 512))[idx];
  ushort4 o = { f2b(a.x + b.x), f2b(a.y + b.y), f2b(a.z + b.z), f2b(a.w + b.w) };
  ((ushort4*)W)[idx] = o;
}

__global__ void prep_cvec(const float* __restrict__ cf_b, const float* __restrict__ sib,
                          float* __restrict__ cvec, float* __restrict__ psum)
{
  const int t = threadIdx.x;   // 512 threads
  cvec[t] = cf_b[t] + cf_b[512 + t] + SIB_SCALE_F * (sib[t] + sib[512 + t]);
  if (t < 3) psum[t] = 0.f;
}

// ---------------------------------------------------------------------------
extern "C" void kernel_launch(void* const* d_in, const int* in_sizes, int n_in,
                              void* d_out, int out_size, void* d_ws, size_t ws_size,
                              hipStream_t stream) {
  const int*   tok    = (const int*)  d_in[0];
  const float* emb    = (const float*)d_in[1];
  const float* proj_w = (const float*)d_in[2];
  const float* proj_b = (const float*)d_in[3];
  const float* cf_w   = (const float*)d_in[4];
  const float* cf_b   = (const float*)d_in[5];
  const float* in_g   = (const float*)d_in[6];
  const float* in_b   = (const float*)d_in[7];
  const float* pde    = (const float*)d_in[8];
  const float* f1w    = (const float*)d_in[9];
  const float* f1b    = (const float*)d_in[10];
  const float* n1g    = (const float*)d_in[11];
  const float* n1b    = (const float*)d_in[12];
  const float* f2w    = (const float*)d_in[13];
  const float* f2bias = (const float*)d_in[14];
  const float* n2g    = (const float*)d_in[15];
  const float* n2b    = (const float*)d_in[16];
  const float* pow_w  = (const float*)d_in[17];
  const float* pow_b  = (const float*)d_in[18];
  const float* sib    = (const float*)d_in[19];
  const float* dep    = (const float*)d_in[20];
  const float* out_w  = (const float*)d_in[21];
  const float* out_b  = (const float*)d_in[22];
  float* out = (float*)d_out;

  char* ws = (char*)d_ws;
  size_t off = 0;
  auto alloc = [&](size_t bytes) -> void* {
    void* p = ws + off;
    off += (bytes + 255) & ~(size_t)255;
    return p;
  };
  u16*   outw_b  = (u16*)  alloc((size_t)32000 * 512 * 2);
  u16*   projw_b = (u16*)  alloc((size_t)512 * 512 * 2);
  u16*   wsum_b  = (u16*)  alloc((size_t)512 * 512 * 2);
  u16*   Ag      = (u16*)  alloc((size_t)4096 * 512 * 2);
  float* h0f     = (float*)alloc((size_t)4096 * 512 * 4);
  u16*   h0b     = (u16*)  alloc((size_t)4096 * 512 * 2);
  float* S1f     = (float*)alloc((size_t)4096 * 512 * 4);
  u16*   S1b     = (u16*)  alloc((size_t)4096 * 512 * 2);
  float* S2f     = (float*)alloc((size_t)4096 * 512 * 4);
  u16*   S2b     = (u16*)  alloc((size_t)4096 * 512 * 2);
  float* S3f     = (float*)alloc((size_t)4096 * 512 * 4);
  u16*   S3b     = (u16*)  alloc((size_t)4096 * 512 * 2);
  float* X       = (float*)alloc((size_t)12288 * 512 * 4);
  float* Y1      = (float*)alloc((size_t)12288 * 256 * 4);
  float* Y2      = (float*)alloc((size_t)12288 * 128 * 4);
  float* y1bias  = (float*)alloc(3 * 256 * 4);
  float* cvec    = (float*)alloc(512 * 4);
  float* psum    = (float*)alloc(256);
  float* coef    = (float*)alloc(256);
  u16*   poolb   = (u16*)  alloc((size_t)4096 * 512 * 2);

  // weight prep
  prep_cvec<<<1, 512, 0, stream>>>(cf_b, sib, cvec, psum);
  prep_wsum<<<256, 256, 0, stream>>>(cf_w, wsum_b);
  prep_y1bias<<<3, 256, 0, stream>>>(f1w, f1b, pde, y1bias);
  f32_to_bf16_vec<<<16000, 256, 0, stream>>>(out_w, outw_b, 4096000);
  f32_to_bf16_vec<<<256, 256, 0, stream>>>(proj_w, projw_b, 65536);
  gather_emb<<<2048, 256, 0, stream>>>(tok, emb, Ag);

  // h0 = emb[tok] @ proj_w^T + proj_b
  gemm_bf16_bt<<<dim3(32, 4), 256, 0, stream>>>(Ag, projw_b, proj_b, 1.f,
                                                h0f, h0b, 4096, 512, 512);
  // S_{l+1} = S_l @ (W_L+W_R)^T + 2^l * c
  gemm_bf16_bt<<<dim3(32, 4), 256, 0, stream>>>(h0b, wsum_b, cvec, 1.f,
                                                S1f, S1b, 4096, 512, 512);
  gemm_bf16_bt<<<dim3(32, 4), 256, 0, stream>>>(S1b, wsum_b, cvec, 2.f,
                                                S2f, S2b, 4096, 512, 512);
  gemm_bf16_bt<<<dim3(32, 4), 256, 0, stream>>>(S2b, wsum_b, cvec, 4.f,
                                                S3f, S3b, 4096, 512, 512);

  // policy (fp32), 3 levels batched as M=12288; pde folded into y1bias
  mean_ln_concat_b<<<3072, 256, 0, stream>>>(h0f, S1f, S2f, dep,
                                             in_g, in_b, X);
  sgemm_bt<<<dim3(192, 4), 256, 0, stream>>>(X, 512, f1w, 640, y1bias, 256,
                                             Y1, 12288, 256, 512);
  ln_relu<256><<<3072, 256, 0, stream>>>(Y1, n1g, n1b);
  sgemm_bt<<<dim3(192, 2), 256, 0, stream>>>(Y1, 256, f2w, 256, f2bias, 0,
                                             Y2, 12288, 128, 256);
  ln_relu<128><<<3072, 256, 0, stream>>>(Y2, n2g, n2b);
  policy_reduce_b<<<3072, 256, 0, stream>>>(Y2, pow_w, pow_b, psum);
  finalize_coef<<<1, 1, 0, stream>>>(psum, coef);

  // pooled = (h0 + a1*S1 + a2*S2 + a3*S3) / cnt  -> bf16
  pool_to_bf16<<<2048, 256, 0, stream>>>(h0f, S1f, S2f, S3f, coef, poolb);

  // out = pooled @ out_w^T + out_b   (4096 x 32000 x 512), pipelined 256^2
  gemm256_bt<<<dim3(16, 125), 512, 0, stream>>>(poolb, outw_b, out_b,
                                                out, 4096, 32000, 512);
}

// Round 4
// 509.602 us; speedup vs baseline: 1.2144x; 1.0077x over previous
//
#include <hip/hip_runtime.h>

typedef unsigned short u16;
using bf16x8 = __attribute__((ext_vector_type(8))) short;
using f32x4  = __attribute__((ext_vector_type(4))) float;

#define SIB_SCALE_F 0.04419417382415922f   // 1/sqrt(512)

__device__ __forceinline__ u16 f2b(float f) {
  unsigned u = __builtin_bit_cast(unsigned, f);
  return (u16)((u + 0x7FFFu + ((u >> 16) & 1u)) >> 16);   // RNE
}

__device__ __forceinline__ float wred(float v) {
  #pragma unroll
  for (int m = 1; m < 64; m <<= 1) v += __shfl_xor(v, m);
  return v;
}

__device__ __forceinline__ void gload16(const void* g, void* l) {
  __builtin_amdgcn_global_load_lds(
      (const __attribute__((address_space(1))) unsigned int*)g,
      (__attribute__((address_space(3))) unsigned int*)l, 16, 0, 0);
}

// ---------------------------------------------------------------------------
// 256x256 bf16 MFMA GEMM, 8-phase-per-2-K-tiles pipeline (T2+T3+T4+T5).
// C[M,N] = A[M,K]@B[N,K]^T + bias[N].  BK=64, 512 thr (8 waves, 2M x 4N),
// per-wave 128x64.  LDS 128 KiB: A[2][256][64] + B[2][256][64], XOR slot
// swizzle (slot ^= row&7), staged via global_load_lds(16B) pre-swizzled src.
// Per K-tile: 4 phases; phase p computes m-pair {2p,2p+1} x n0-3 x kk0,1
// (16 MFMA).  B frags read once at ph0 (B region free after ph0).
// Staging (during tile t, buf b=t&1):
//   ph0: A-h0 of t+1 -> A-buf(b^1)   [free since end of tile t-1]
//   ph1: A-h1 of t+1
//   ph2: B-h0 of t+2 -> B-buf(b)     [free after tile t ph0]
//   ph3: B-h1 of t+2; vmcnt(4)       [only the 2 B-stages may stay in flight]
// M%256==0, N%256==0, K%64==0.
// ---------------------------------------------------------------------------
__global__ __launch_bounds__(512, 2) void gemm256_bt(
    const u16* __restrict__ A, const u16* __restrict__ B,
    const float* __restrict__ bias,
    float* __restrict__ C, int M, int N, int K)
{
  __shared__ u16 lds[65536];   // A: [0,32768) ; B: [32768,65536)  (u16 units)
  const int t = threadIdx.x, w = t >> 6, lane = t & 63;
  const int wm = w >> 2, wn = w & 3;
  const int r16 = lane & 15, ks = lane >> 4;

  // XCD-chunked bijective swizzle (grid % 8 == 0), bx fastest = B-panel reuse
  const int nb = gridDim.x * gridDim.y;
  const int lid = blockIdx.y * gridDim.x + blockIdx.x;
  const int chunk = nb >> 3;
  const int nlid = (lid & 7) * chunk + (lid >> 3);
  const int bm = (nlid % gridDim.x) * 256;
  const int bn = (nlid / gridDim.x) * 256;

  const int NT = K >> 6;

  // stage one half-tile (128 rows x 64 cols): 2 x gload16 per thread.
  auto stageH = [&](const u16* __restrict__ G, int grow0, int kt, int half, int opBase) {
    const int k0 = kt << 6;
    u16* dst = lds + opBase + ((kt & 1) << 14) + (half << 13);
    #pragma unroll
    for (int j = 0; j < 2; ++j) {
      const int r = half * 128 + j * 64 + w * 8 + (lane >> 3);
      const int s = (lane & 7) ^ (r & 7);          // pre-swizzled source slot
      gload16(G + (size_t)(grow0 + r) * K + k0 + s * 8,
              dst + j * 4096 + w * 512);           // wave-uniform LDS dest
    }
  };

  f32x4 acc[8][4];
  #pragma unroll
  for (int m = 0; m < 8; ++m)
    #pragma unroll
    for (int n = 0; n < 4; ++n) {
      f32x4 z = {0.f, 0.f, 0.f, 0.f};
      acc[m][n] = z;
    }

  // prologue: t0 A(h0,h1), t0 B(h0,h1), t1 B(h0,h1)
  stageH(A, bm, 0, 0, 0);
  stageH(A, bm, 0, 1, 0);
  stageH(B, bn, 0, 0, 32768);
  stageH(B, bn, 0, 1, 32768);
  if (NT > 1) {
    stageH(B, bn, 1, 0, 32768);
    stageH(B, bn, 1, 1, 32768);
    asm volatile("s_waitcnt vmcnt(4)" ::: "memory");   // t0 fully landed
  } else {
    asm volatile("s_waitcnt vmcnt(0)" ::: "memory");
  }
  __builtin_amdgcn_sched_barrier(0);
  __builtin_amdgcn_s_barrier();

  for (int kt = 0; kt < NT; ++kt) {
    const u16* Ab = lds + ((kt & 1) << 14);
    const u16* Bb = lds + 32768 + ((kt & 1) << 14);
    bf16x8 bfr[4][2];

    #pragma unroll
    for (int p = 0; p < 4; ++p) {
      // ---- ds-load register subtile ----
      bf16x8 af2[2][2];
      #pragma unroll
      for (int i = 0; i < 2; ++i) {
        const int row = wm * 128 + (2 * p + i) * 16 + r16;
        af2[i][0] = *(const bf16x8*)(Ab + row * 64 + ((ks ^ (row & 7)) << 3));
        af2[i][1] = *(const bf16x8*)(Ab + row * 64 + (((4 + ks) ^ (row & 7)) << 3));
      }
      if (p == 0) {
        #pragma unroll
        for (int n = 0; n < 4; ++n) {
          const int row = wn * 64 + n * 16 + r16;
          bfr[n][0] = *(const bf16x8*)(Bb + row * 64 + ((ks ^ (row & 7)) << 3));
          bfr[n][1] = *(const bf16x8*)(Bb + row * 64 + (((4 + ks) ^ (row & 7)) << 3));
        }
      }
      // ---- stage one half-tile (lifetime-safe targets, see header) ----
      if (p == 0 && kt + 1 < NT) stageH(A, bm, kt + 1, 0, 0);
      if (p == 1 && kt + 1 < NT) stageH(A, bm, kt + 1, 1, 0);
      if (p == 2 && kt + 2 < NT) stageH(B, bn, kt + 2, 0, 32768);
      if (p == 3) {
        if (kt + 2 < NT) {
          stageH(B, bn, kt + 2, 1, 32768);
          asm volatile("s_waitcnt vmcnt(4)" ::: "memory");  // tile kt+1 landed
        } else {
          asm volatile("s_waitcnt vmcnt(0)" ::: "memory");
        }
        __builtin_amdgcn_sched_barrier(0);
      }
      __builtin_amdgcn_s_barrier();
      asm volatile("s_waitcnt lgkmcnt(0)" ::: "memory");
      __builtin_amdgcn_sched_barrier(0);
      __builtin_amdgcn_s_setprio(1);
      #pragma unroll
      for (int i = 0; i < 2; ++i)
        #pragma unroll
        for (int n = 0; n < 4; ++n) {
          acc[2 * p + i][n] = __builtin_amdgcn_mfma_f32_16x16x32_bf16(
              af2[i][0], bfr[n][0], acc[2 * p + i][n], 0, 0, 0);
          acc[2 * p + i][n] = __builtin_amdgcn_mfma_f32_16x16x32_bf16(
              af2[i][1], bfr[n][1], acc[2 * p + i][n], 0, 0, 0);
        }
      __builtin_amdgcn_s_setprio(0);
      __builtin_amdgcn_s_barrier();
    }
  }

  // epilogue: C/D layout col = lane&15, row = (lane>>4)*4 + reg
  #pragma unroll
  for (int n = 0; n < 4; ++n) {
    const int gcol = bn + wn * 64 + n * 16 + r16;
    const float bv = bias[gcol];
    #pragma unroll
    for (int m = 0; m < 8; ++m) {
      const int grow0 = bm + wm * 128 + m * 16 + ks * 4;
      #pragma unroll
      for (int r = 0; r < 4; ++r)
        C[(size_t)(grow0 + r) * N + gcol] = acc[m][n][r] + bv;
    }
  }
}

// ---------------------------------------------------------------------------
// bf16 MFMA GEMM (chain path): C[M,N] = A@B^T + bscale*bias, 128x128, BK=32.
// ---------------------------------------------------------------------------
__global__ __launch_bounds__(256) void gemm_bf16_bt(
    const u16* __restrict__ A, const u16* __restrict__ B,
    const float* __restrict__ bias, float bscale,
    float* __restrict__ C, u16* __restrict__ Cb,
    int M, int N, int K)
{
  __shared__ u16 ldsA[128 * 32];
  __shared__ u16 ldsB[128 * 32];
  const int t = threadIdx.x;
  const int w = t >> 6;
  const int lane = t & 63;
  const int wr = w >> 1, wc = w & 1;

  const int nb = gridDim.x * gridDim.y;
  const int lid = blockIdx.y * gridDim.x + blockIdx.x;
  const int chunk = nb >> 3;
  const int nlid = (lid & 7) * chunk + (lid >> 3);
  const int bx = nlid % gridDim.x, by = nlid / gridDim.x;

  const int bm = bx * 128, bn = by * 128;
  const int r16 = lane & 15, ks = lane >> 4;
  const int srow = t >> 2, sslot = t & 3;

  f32x4 acc[4][4];
  #pragma unroll
  for (int m = 0; m < 4; ++m)
    #pragma unroll
    for (int n = 0; n < 4; ++n) {
      f32x4 z = {0.f, 0.f, 0.f, 0.f};
      acc[m][n] = z;
    }

  for (int k0 = 0; k0 < K; k0 += 32) {
    if (k0) __syncthreads();
    #pragma unroll
    for (int i = 0; i < 2; ++i) {
      const int row = srow + i * 64;
      const int sl = sslot ^ ((row >> 1) & 3);
      gload16(A + (size_t)(bm + row) * K + k0 + sl * 8,
              ldsA + (i * 2048 + w * 512));
      gload16(B + (size_t)(bn + row) * K + k0 + sl * 8,
              ldsB + (i * 2048 + w * 512));
    }
    __syncthreads();

    bf16x8 af[4], bfr[4];
    #pragma unroll
    for (int m = 0; m < 4; ++m) {
      const int row = wr * 64 + m * 16 + r16;
      af[m] = *(const bf16x8*)(ldsA + row * 32 + ((ks ^ ((row >> 1) & 3)) << 3));
    }
    #pragma unroll
    for (int n = 0; n < 4; ++n) {
      const int row = wc * 64 + n * 16 + r16;
      bfr[n] = *(const bf16x8*)(ldsB + row * 32 + ((ks ^ ((row >> 1) & 3)) << 3));
    }
    #pragma unroll
    for (int m = 0; m < 4; ++m)
      #pragma unroll
      for (int n = 0; n < 4; ++n)
        acc[m][n] = __builtin_amdgcn_mfma_f32_16x16x32_bf16(af[m], bfr[n], acc[m][n], 0, 0, 0);
  }

  #pragma unroll
  for (int m = 0; m < 4; ++m) {
    const int grow0 = bm + wr * 64 + m * 16 + ks * 4;
    #pragma unroll
    for (int n = 0; n < 4; ++n) {
      const int gcol = bn + wc * 64 + n * 16 + r16;
      const float bv = bias ? bias[gcol] * bscale : 0.f;
      #pragma unroll
      for (int r = 0; r < 4; ++r) {
        const float v = acc[m][n][r] + bv;
        const size_t idx = (size_t)(grow0 + r) * N + gcol;
        C[idx] = v;
        if (Cb) Cb[idx] = f2b(v);
      }
    }
  }
}

// ---------------------------------------------------------------------------
// fp32 SGEMM (policy path): C = A@B^T + bias[level-select]
// 64x64 tile, BK=16, 256 threads, 4x4/thread, float4 staging.
// ---------------------------------------------------------------------------
__global__ __launch_bounds__(256) void sgemm_bt(
    const float* __restrict__ A, int lda,
    const float* __restrict__ B, int ldb,
    const float* __restrict__ bias, int bias_lvl,
    float* __restrict__ C, int M, int N, int K)
{
  __shared__ float As[16][68];
  __shared__ float Bs[16][68];
  const int t = threadIdx.x;
  const int tx = t & 15, ty = t >> 4;
  const int bm = blockIdx.x * 64, bn = blockIdx.y * 64;
  const float* be = bias + (size_t)(bm >> 12) * bias_lvl;
  const int srow = t >> 2, skq = (t & 3) * 4;
  float acc[4][4] = {};
  for (int k0 = 0; k0 < K; k0 += 16) {
    if (k0) __syncthreads();
    {
      const float4 av = *(const float4*)&A[(size_t)(bm + srow) * lda + k0 + skq];
      const float4 bv = *(const float4*)&B[(size_t)(bn + srow) * ldb + k0 + skq];
      As[skq + 0][srow] = av.x; As[skq + 1][srow] = av.y;
      As[skq + 2][srow] = av.z; As[skq + 3][srow] = av.w;
      Bs[skq + 0][srow] = bv.x; Bs[skq + 1][srow] = bv.y;
      Bs[skq + 2][srow] = bv.z; Bs[skq + 3][srow] = bv.w;
    }
    __syncthreads();
    #pragma unroll
    for (int kk = 0; kk < 16; ++kk) {
      const float4 av = *(const float4*)&As[kk][ty * 4];
      const float4 bv = *(const float4*)&Bs[kk][tx * 4];
      const float ar[4] = {av.x, av.y, av.z, av.w};
      const float br[4] = {bv.x, bv.y, bv.z, bv.w};
      #pragma unroll
      for (int i = 0; i < 4; ++i)
        #pragma unroll
        for (int j = 0; j < 4; ++j)
          acc[i][j] += ar[i] * br[j];
    }
  }
  #pragma unroll
  for (int i = 0; i < 4; ++i) {
    const int grow = bm + ty * 4 + i;
    #pragma unroll
    for (int j = 0; j < 4; ++j) {
      const int gcol = bn + tx * 4 + j;
      C[(size_t)grow * N + gcol] = acc[i][j] + be[gcol];
    }
  }
}

// y1bias[l][j] = f1b[j] + sum_k f1w[j][512+k] * pde[l][k]   (3 x 256)
__global__ void prep_y1bias(const float* __restrict__ f1w, const float* __restrict__ f1b,
                            const float* __restrict__ pde, float* __restrict__ y1bias)
{
  const int l = blockIdx.x, j = threadIdx.x;
  const float* wrow = f1w + (size_t)j * 640 + 512;
  const float* p = pde + l * 128;
  float s = f1b[j];
  #pragma unroll 4
  for (int k = 0; k < 128; ++k) s += wrow[k] * p[k];
  y1bias[l * 256 + j] = s;
}

// ---------------------------------------------------------------------------
// batched policy input over 3 levels: row g = l*4096+n
// X[g, 0:512] = LN(S_l[n]/2^l + 0.01*dep_l)*g+b   (stride 512; pde folded out)
// ---------------------------------------------------------------------------
__global__ __launch_bounds__(256) void mean_ln_concat_b(
    const float* __restrict__ S0, const float* __restrict__ S1,
    const float* __restrict__ S2,
    const float* __restrict__ dep,
    const float* __restrict__ g, const float* __restrict__ b,
    float* __restrict__ X)
{
  const int wid = threadIdx.x >> 6, lane = threadIdx.x & 63;
  const int gr = blockIdx.x * 4 + wid;          // 0..12287
  const int l = gr >> 12, n = gr & 4095;
  const float* Sr = (l == 0 ? S0 : l == 1 ? S1 : S2) + (size_t)n * 512;
  const float invM = (l == 0 ? 1.f : l == 1 ? 0.5f : 0.25f);
  const float* depl = dep + 512 * l;
  const int c0 = lane * 8;
  float x[8];
  float s = 0.f, sq = 0.f;
  #pragma unroll
  for (int i = 0; i < 8; ++i) {
    const float v = Sr[c0 + i] * invM + 0.01f * depl[c0 + i];
    x[i] = v; s += v; sq += v * v;
  }
  s = wred(s); sq = wred(sq);
  const float mean = s * (1.f / 512.f);
  const float var = sq * (1.f / 512.f) - mean * mean;
  const float rs = rsqrtf(var + 1e-5f);
  float* Xr = X + (size_t)gr * 512;
  #pragma unroll
  for (int i = 0; i < 8; ++i) {
    const int c = c0 + i;
    Xr[c] = (x[i] - mean) * rs * g[c] + b[c];
  }
}

template <int C>
__global__ __launch_bounds__(256) void ln_relu(
    float* __restrict__ X, const float* __restrict__ g, const float* __restrict__ b)
{
  constexpr int E = C / 64;
  const int wid = threadIdx.x >> 6, lane = threadIdx.x & 63;
  const int n = blockIdx.x * 4 + wid;
  float* Xr = X + (size_t)n * C;
  float x[E];
  float s = 0.f, sq = 0.f;
  #pragma unroll
  for (int i = 0; i < E; ++i) {
    x[i] = Xr[lane * E + i]; s += x[i]; sq += x[i] * x[i];
  }
  s = wred(s); sq = wred(sq);
  const float mean = s * (1.f / (float)C);
  const float var = sq * (1.f / (float)C) - mean * mean;
  const float rs = rsqrtf(var + 1e-5f);
  #pragma unroll
  for (int i = 0; i < E; ++i) {
    const int c = lane * E + i;
    Xr[c] = fmaxf((x[i] - mean) * rs * g[c] + b[c], 0.f);
  }
}

__global__ __launch_bounds__(256) void policy_reduce_b(
    const float* __restrict__ Y2, const float* __restrict__ pw,
    const float* __restrict__ pb, float* __restrict__ psum)
{
  __shared__ float part[4];
  const int wid = threadIdx.x >> 6, lane = threadIdx.x & 63;
  const int gr = blockIdx.x * 4 + wid;
  const float* r = Y2 + (size_t)gr * 128;
  float z = r[lane * 2] * pw[lane * 2] + r[lane * 2 + 1] * pw[lane * 2 + 1];
  z = wred(z);
  if (lane == 0) {
    const float p = 1.f / (1.f + expf(-(z + pb[0])));
    part[wid] = fminf(fmaxf(p, 1e-7f), 1.f - 1e-7f);
  }
  __syncthreads();
  if (threadIdx.x == 0)
    atomicAdd(psum + (gr >> 12), part[0] + part[1] + part[2] + part[3]);
}

__global__ void finalize_coef(const float* __restrict__ psum, float* __restrict__ coef)
{
  float alive = 1.f, cnt = 1.f;
  #pragma unroll
  for (int l = 0; l < 3; ++l) {
    const float pm = psum[l] * (1.f / 4096.f);
    if (!(pm >= 0.5f)) alive = 0.f;
    coef[l] = alive;
    cnt += alive * (float)(2 << l);
  }
  coef[3] = 1.f / fmaxf(cnt, 1e-8f);
}

__global__ __launch_bounds__(256) void pool_to_bf16(
    const float* __restrict__ h0, const float* __restrict__ S1,
    const float* __restrict__ S2, const float* __restrict__ S3,
    const float* __restrict__ coef, u16* __restrict__ P)
{
  const int idx = blockIdx.x * 256 + threadIdx.x;   // over 4096*512/4
  const float c0 = coef[0], c1 = coef[1], c2 = coef[2], inv = coef[3];
  const float4 a  = ((const float4*)h0)[idx];
  const float4 s1 = ((const float4*)S1)[idx];
  const float4 s2 = ((const float4*)S2)[idx];
  const float4 s3 = ((const float4*)S3)[idx];
  ushort4 o;
  o.x = f2b((a.x + c0 * s1.x + c1 * s2.x + c2 * s3.x) * inv);
  o.y = f2b((a.y + c0 * s1.y + c1 * s2.y + c2 * s3.y) * inv);
  o.z = f2b((a.z + c0 * s1.z + c1 * s2.z + c2 * s3.z) * inv);
  o.w = f2b((a.w + c0 * s1.w + c1 * s2.w + c2 * s3.w) * inv);
  ((ushort4*)P)[idx] = o;
}

__global__ __launch_bounds__(256) void gather_emb(
    const int* __restrict__ tok, const float* __restrict__ emb, u16* __restrict__ Ag)
{
  const int idx = blockIdx.x * 256 + threadIdx.x;   // over 4096*128
  const int n = idx >> 7, c4 = idx & 127;
  const float4 v = ((const float4*)(emb + (size_t)tok[n] * 512))[c4];
  ushort4 o = { f2b(v.x), f2b(v.y), f2b(v.z), f2b(v.w) };
  ((ushort4*)(Ag + (size_t)n * 512))[c4] = o;
}

__global__ __launch_bounds__(256) void f32_to_bf16_vec(
    const float* __restrict__ src, u16* __restrict__ dst, int n4)
{
  const int idx = blockIdx.x * 256 + threadIdx.x;
  if (idx >= n4) return;
  const float4 v = ((const float4*)src)[idx];
  ushort4 o = { f2b(v.x), f2b(v.y), f2b(v.z), f2b(v.w) };
  ((ushort4*)dst)[idx] = o;
}

__global__ __launch_bounds__(256) void prep_wsum(
    const float* __restrict__ cf_w, u16* __restrict__ W)
{
  const int idx = blockIdx.x * 256 + threadIdx.x;   // over 512*512/4
  const float4 a = ((const float4*)cf_w)[idx];
  const float4 b = ((const float4*)(cf_w + 512 * 512))[idx];
  ushort4 o = { f2b(a.x + b.x), f2b(a.y + b.y), f2b(a.z + b.z), f2b(a.w + b.w) };
  ((ushort4*)W)[idx] = o;
}

__global__ void prep_cvec(const float* __restrict__ cf_b, const float* __restrict__ sib,
                          float* __restrict__ cvec, float* __restrict__ psum)
{
  const int t = threadIdx.x;   // 512 threads
  cvec[t] = cf_b[t] + cf_b[512 + t] + SIB_SCALE_F * (sib[t] + sib[512 + t]);
  if (t < 3) psum[t] = 0.f;
}

// ---------------------------------------------------------------------------
extern "C" void kernel_launch(void* const* d_in, const int* in_sizes, int n_in,
                              void* d_out, int out_size, void* d_ws, size_t ws_size,
                              hipStream_t stream) {
  const int*   tok    = (const int*)  d_in[0];
  const float* emb    = (const float*)d_in[1];
  const float* proj_w = (const float*)d_in[2];
  const float* proj_b = (const float*)d_in[3];
  const float* cf_w   = (const float*)d_in[4];
  const float* cf_b   = (const float*)d_in[5];
  const float* in_g   = (const float*)d_in[6];
  const float* in_b   = (const float*)d_in[7];
  const float* pde    = (const float*)d_in[8];
  const float* f1w    = (const float*)d_in[9];
  const float* f1b    = (const float*)d_in[10];
  const float* n1g    = (const float*)d_in[11];
  const float* n1b    = (const float*)d_in[12];
  const float* f2w    = (const float*)d_in[13];
  const float* f2bias = (const float*)d_in[14];
  const float* n2g    = (const float*)d_in[15];
  const float* n2b    = (const float*)d_in[16];
  const float* pow_w  = (const float*)d_in[17];
  const float* pow_b  = (const float*)d_in[18];
  const float* sib    = (const float*)d_in[19];
  const float* dep    = (const float*)d_in[20];
  const float* out_w  = (const float*)d_in[21];
  const float* out_b  = (const float*)d_in[22];
  float* out = (float*)d_out;

  char* ws = (char*)d_ws;
  size_t off = 0;
  auto alloc = [&](size_t bytes) -> void* {
    void* p = ws + off;
    off += (bytes + 255) & ~(size_t)255;
    return p;
  };
  u16*   outw_b  = (u16*)  alloc((size_t)32000 * 512 * 2);
  u16*   projw_b = (u16*)  alloc((size_t)512 * 512 * 2);
  u16*   wsum_b  = (u16*)  alloc((size_t)512 * 512 * 2);
  u16*   Ag      = (u16*)  alloc((size_t)4096 * 512 * 2);
  float* h0f     = (float*)alloc((size_t)4096 * 512 * 4);
  u16*   h0b     = (u16*)  alloc((size_t)4096 * 512 * 2);
  float* S1f     = (float*)alloc((size_t)4096 * 512 * 4);
  u16*   S1b     = (u16*)  alloc((size_t)4096 * 512 * 2);
  float* S2f     = (float*)alloc((size_t)4096 * 512 * 4);
  u16*   S2b     = (u16*)  alloc((size_t)4096 * 512 * 2);
  float* S3f     = (float*)alloc((size_t)4096 * 512 * 4);
  u16*   S3b     = (u16*)  alloc((size_t)4096 * 512 * 2);
  float* X       = (float*)alloc((size_t)12288 * 512 * 4);
  float* Y1      = (float*)alloc((size_t)12288 * 256 * 4);
  float* Y2      = (float*)alloc((size_t)12288 * 128 * 4);
  float* y1bias  = (float*)alloc(3 * 256 * 4);
  float* cvec    = (float*)alloc(512 * 4);
  float* psum    = (float*)alloc(256);
  float* coef    = (float*)alloc(256);
  u16*   poolb   = (u16*)  alloc((size_t)4096 * 512 * 2);

  // weight prep
  prep_cvec<<<1, 512, 0, stream>>>(cf_b, sib, cvec, psum);
  prep_wsum<<<256, 256, 0, stream>>>(cf_w, wsum_b);
  prep_y1bias<<<3, 256, 0, stream>>>(f1w, f1b, pde, y1bias);
  f32_to_bf16_vec<<<16000, 256, 0, stream>>>(out_w, outw_b, 4096000);
  f32_to_bf16_vec<<<256, 256, 0, stream>>>(proj_w, projw_b, 65536);
  gather_emb<<<2048, 256, 0, stream>>>(tok, emb, Ag);

  // h0 = emb[tok] @ proj_w^T + proj_b
  gemm_bf16_bt<<<dim3(32, 4), 256, 0, stream>>>(Ag, projw_b, proj_b, 1.f,
                                                h0f, h0b, 4096, 512, 512);
  // S_{l+1} = S_l @ (W_L+W_R)^T + 2^l * c
  gemm_bf16_bt<<<dim3(32, 4), 256, 0, stream>>>(h0b, wsum_b, cvec, 1.f,
                                                S1f, S1b, 4096, 512, 512);
  gemm_bf16_bt<<<dim3(32, 4), 256, 0, stream>>>(S1b, wsum_b, cvec, 2.f,
                                                S2f, S2b, 4096, 512, 512);
  gemm_bf16_bt<<<dim3(32, 4), 256, 0, stream>>>(S2b, wsum_b, cvec, 4.f,
                                                S3f, S3b, 4096, 512, 512);

  // policy (fp32), 3 levels batched as M=12288; pde folded into y1bias
  mean_ln_concat_b<<<3072, 256, 0, stream>>>(h0f, S1f, S2f, dep,
                                             in_g, in_b, X);
  sgemm_bt<<<dim3(192, 4), 256, 0, stream>>>(X, 512, f1w, 640, y1bias, 256,
                                             Y1, 12288, 256, 512);
  ln_relu<256><<<3072, 256, 0, stream>>>(Y1, n1g, n1b);
  sgemm_bt<<<dim3(192, 2), 256, 0, stream>>>(Y1, 256, f2w, 256, f2bias, 0,
                                             Y2, 12288, 128, 256);
  ln_relu<128><<<3072, 256, 0, stream>>>(Y2, n2g, n2b);
  policy_reduce_b<<<3072, 256, 0, stream>>>(Y2, pow_w, pow_b, psum);
  finalize_coef<<<1, 1, 0, stream>>>(psum, coef);

  // pooled = (h0 + a1*S1 + a2*S2 + a3*S3) / cnt  -> bf16
  pool_to_bf16<<<2048, 256, 0, stream>>>(h0f, S1f, S2f, S3f, coef, poolb);

  // out = pooled @ out_w^T + out_b   (4096 x 32000 x 512), 8-phase 256^2
  gemm256_bt<<<dim3(16, 125), 512, 0, stream>>>(poolb, outw_b, out_b,
                                                out, 4096, 32000, 512);
}

// Round 5
// 448.502 us; speedup vs baseline: 1.3798x; 1.1362x over previous
//
#include <hip/hip_runtime.h>

typedef unsigned short u16;
using bf16x8 = __attribute__((ext_vector_type(8))) short;
using f32x4  = __attribute__((ext_vector_type(4))) float;

#define SIB_SCALE_F 0.04419417382415922f   // 1/sqrt(512)

__device__ __forceinline__ u16 f2b(float f) {
  unsigned u = __builtin_bit_cast(unsigned, f);
  return (u16)((u + 0x7FFFu + ((u >> 16) & 1u)) >> 16);   // RNE
}

__device__ __forceinline__ float wred(float v) {
  #pragma unroll
  for (int m = 1; m < 64; m <<= 1) v += __shfl_xor(v, m);
  return v;
}

__device__ __forceinline__ void gload16(const void* g, void* l) {
  __builtin_amdgcn_global_load_lds(
      (const __attribute__((address_space(1))) unsigned int*)g,
      (__attribute__((address_space(3))) unsigned int*)l, 16, 0, 0);
}

// ---------------------------------------------------------------------------
// 256x256 bf16 MFMA GEMM, 8-phase pipeline (T2+T3+T4+T5).  See R3/R4 notes.
// ---------------------------------------------------------------------------
__global__ __launch_bounds__(512, 2) void gemm256_bt(
    const u16* __restrict__ A, const u16* __restrict__ B,
    const float* __restrict__ bias,
    float* __restrict__ C, int M, int N, int K)
{
  __shared__ u16 lds[65536];   // A: [0,32768) ; B: [32768,65536)  (u16 units)
  const int t = threadIdx.x, w = t >> 6, lane = t & 63;
  const int wm = w >> 2, wn = w & 3;
  const int r16 = lane & 15, ks = lane >> 4;

  const int nb = gridDim.x * gridDim.y;
  const int lid = blockIdx.y * gridDim.x + blockIdx.x;
  const int chunk = nb >> 3;
  const int nlid = (lid & 7) * chunk + (lid >> 3);
  const int bm = (nlid % gridDim.x) * 256;
  const int bn = (nlid / gridDim.x) * 256;

  const int NT = K >> 6;

  auto stageH = [&](const u16* __restrict__ G, int grow0, int kt, int half, int opBase) {
    const int k0 = kt << 6;
    u16* dst = lds + opBase + ((kt & 1) << 14) + (half << 13);
    #pragma unroll
    for (int j = 0; j < 2; ++j) {
      const int r = half * 128 + j * 64 + w * 8 + (lane >> 3);
      const int s = (lane & 7) ^ (r & 7);
      gload16(G + (size_t)(grow0 + r) * K + k0 + s * 8,
              dst + j * 4096 + w * 512);
    }
  };

  f32x4 acc[8][4];
  #pragma unroll
  for (int m = 0; m < 8; ++m)
    #pragma unroll
    for (int n = 0; n < 4; ++n) {
      f32x4 z = {0.f, 0.f, 0.f, 0.f};
      acc[m][n] = z;
    }

  stageH(A, bm, 0, 0, 0);
  stageH(A, bm, 0, 1, 0);
  stageH(B, bn, 0, 0, 32768);
  stageH(B, bn, 0, 1, 32768);
  if (NT > 1) {
    stageH(B, bn, 1, 0, 32768);
    stageH(B, bn, 1, 1, 32768);
    asm volatile("s_waitcnt vmcnt(4)" ::: "memory");
  } else {
    asm volatile("s_waitcnt vmcnt(0)" ::: "memory");
  }
  __builtin_amdgcn_sched_barrier(0);
  __builtin_amdgcn_s_barrier();

  for (int kt = 0; kt < NT; ++kt) {
    const u16* Ab = lds + ((kt & 1) << 14);
    const u16* Bb = lds + 32768 + ((kt & 1) << 14);
    bf16x8 bfr[4][2];

    #pragma unroll
    for (int p = 0; p < 4; ++p) {
      bf16x8 af2[2][2];
      #pragma unroll
      for (int i = 0; i < 2; ++i) {
        const int row = wm * 128 + (2 * p + i) * 16 + r16;
        af2[i][0] = *(const bf16x8*)(Ab + row * 64 + ((ks ^ (row & 7)) << 3));
        af2[i][1] = *(const bf16x8*)(Ab + row * 64 + (((4 + ks) ^ (row & 7)) << 3));
      }
      if (p == 0) {
        #pragma unroll
        for (int n = 0; n < 4; ++n) {
          const int row = wn * 64 + n * 16 + r16;
          bfr[n][0] = *(const bf16x8*)(Bb + row * 64 + ((ks ^ (row & 7)) << 3));
          bfr[n][1] = *(const bf16x8*)(Bb + row * 64 + (((4 + ks) ^ (row & 7)) << 3));
        }
      }
      if (p == 0 && kt + 1 < NT) stageH(A, bm, kt + 1, 0, 0);
      if (p == 1 && kt + 1 < NT) stageH(A, bm, kt + 1, 1, 0);
      if (p == 2 && kt + 2 < NT) stageH(B, bn, kt + 2, 0, 32768);
      if (p == 3) {
        if (kt + 2 < NT) {
          stageH(B, bn, kt + 2, 1, 32768);
          asm volatile("s_waitcnt vmcnt(4)" ::: "memory");
        } else {
          asm volatile("s_waitcnt vmcnt(0)" ::: "memory");
        }
        __builtin_amdgcn_sched_barrier(0);
      }
      __builtin_amdgcn_s_barrier();
      asm volatile("s_waitcnt lgkmcnt(0)" ::: "memory");
      __builtin_amdgcn_sched_barrier(0);
      __builtin_amdgcn_s_setprio(1);
      #pragma unroll
      for (int i = 0; i < 2; ++i)
        #pragma unroll
        for (int n = 0; n < 4; ++n) {
          acc[2 * p + i][n] = __builtin_amdgcn_mfma_f32_16x16x32_bf16(
              af2[i][0], bfr[n][0], acc[2 * p + i][n], 0, 0, 0);
          acc[2 * p + i][n] = __builtin_amdgcn_mfma_f32_16x16x32_bf16(
              af2[i][1], bfr[n][1], acc[2 * p + i][n], 0, 0, 0);
        }
      __builtin_amdgcn_s_setprio(0);
      __builtin_amdgcn_s_barrier();
    }
  }

  #pragma unroll
  for (int n = 0; n < 4; ++n) {
    const int gcol = bn + wn * 64 + n * 16 + r16;
    const float bv = bias[gcol];
    #pragma unroll
    for (int m = 0; m < 8; ++m) {
      const int grow0 = bm + wm * 128 + m * 16 + ks * 4;
      #pragma unroll
      for (int r = 0; r < 4; ++r)
        C[(size_t)(grow0 + r) * N + gcol] = acc[m][n][r] + bv;
    }
  }
}

// ---------------------------------------------------------------------------
// bf16 MFMA GEMM, 128x128 tile, BK=32.  C = A@B^T + bscale*bias[level sel].
// GATHER=true: A rows come from Afp[tok[row]] (fp32), converted in staging.
// bias_eff = bias + (bm>>12)*blvl.
// ---------------------------------------------------------------------------
template <bool GATHER>
__global__ __launch_bounds__(256) void gemm_bf16_bt(
    const float* __restrict__ Afp, const int* __restrict__ tok,
    const u16* __restrict__ A, const u16* __restrict__ B,
    const float* __restrict__ bias, int blvl, float bscale,
    float* __restrict__ C, u16* __restrict__ Cb,
    int M, int N, int K)
{
  __shared__ u16 ldsA[128 * 32];
  __shared__ u16 ldsB[128 * 32];
  const int t = threadIdx.x;
  const int w = t >> 6;
  const int lane = t & 63;
  const int wr = w >> 1, wc = w & 1;

  const int nb = gridDim.x * gridDim.y;
  const int lid = blockIdx.y * gridDim.x + blockIdx.x;
  const int chunk = nb >> 3;
  const int nlid = (lid & 7) * chunk + (lid >> 3);
  const int bx = nlid % gridDim.x, by = nlid / gridDim.x;

  const int bm = bx * 128, bn = by * 128;
  const int r16 = lane & 15, ks = lane >> 4;
  const int srow = t >> 2, sslot = t & 3;

  f32x4 acc[4][4];
  #pragma unroll
  for (int m = 0; m < 4; ++m)
    #pragma unroll
    for (int n = 0; n < 4; ++n) {
      f32x4 z = {0.f, 0.f, 0.f, 0.f};
      acc[m][n] = z;
    }

  for (int k0 = 0; k0 < K; k0 += 32) {
    if (k0) __syncthreads();
    #pragma unroll
    for (int i = 0; i < 2; ++i) {
      const int row = srow + i * 64;
      const int sl = sslot ^ ((row >> 1) & 3);
      if constexpr (GATHER) {
        const float* src = Afp + (size_t)tok[bm + row] * 512 + k0 + sl * 8;
        const float4 a0 = *(const float4*)src;
        const float4 a1 = *(const float4*)(src + 4);
        bf16x8 v;
        v[0] = (short)f2b(a0.x); v[1] = (short)f2b(a0.y);
        v[2] = (short)f2b(a0.z); v[3] = (short)f2b(a0.w);
        v[4] = (short)f2b(a1.x); v[5] = (short)f2b(a1.y);
        v[6] = (short)f2b(a1.z); v[7] = (short)f2b(a1.w);
        *(bf16x8*)(ldsA + i * 2048 + w * 512 + lane * 8) = v;
      } else {
        gload16(A + (size_t)(bm + row) * K + k0 + sl * 8,
                ldsA + (i * 2048 + w * 512));
      }
      gload16(B + (size_t)(bn + row) * K + k0 + sl * 8,
              ldsB + (i * 2048 + w * 512));
    }
    __syncthreads();

    bf16x8 af[4], bfr[4];
    #pragma unroll
    for (int m = 0; m < 4; ++m) {
      const int row = wr * 64 + m * 16 + r16;
      af[m] = *(const bf16x8*)(ldsA + row * 32 + ((ks ^ ((row >> 1) & 3)) << 3));
    }
    #pragma unroll
    for (int n = 0; n < 4; ++n) {
      const int row = wc * 64 + n * 16 + r16;
      bfr[n] = *(const bf16x8*)(ldsB + row * 32 + ((ks ^ ((row >> 1) & 3)) << 3));
    }
    #pragma unroll
    for (int m = 0; m < 4; ++m)
      #pragma unroll
      for (int n = 0; n < 4; ++n)
        acc[m][n] = __builtin_amdgcn_mfma_f32_16x16x32_bf16(af[m], bfr[n], acc[m][n], 0, 0, 0);
  }

  const float* be = bias + (size_t)(bm >> 12) * blvl;
  #pragma unroll
  for (int m = 0; m < 4; ++m) {
    const int grow0 = bm + wr * 64 + m * 16 + ks * 4;
    #pragma unroll
    for (int n = 0; n < 4; ++n) {
      const int gcol = bn + wc * 64 + n * 16 + r16;
      const float bv = be[gcol] * bscale;
      #pragma unroll
      for (int r = 0; r < 4; ++r) {
        const float v = acc[m][n][r] + bv;
        const size_t idx = (size_t)(grow0 + r) * N + gcol;
        C[idx] = v;
        if (Cb) Cb[idx] = f2b(v);
      }
    }
  }
}

// ---------------------------------------------------------------------------
// fused weight prep, role-dispatched by blockIdx.x (grid 676):
//  [0,256)   wsum_b   = bf16(cf_w[0] + cf_w[1])            (65536 float4)
//  [256,512) projw_b  = bf16(proj_w)                        (65536 float4)
//  [512,640) f1w512b  = bf16(f1w[:, :512])  stride 640->512 (32768 float4)
//  [640,672) f2wb     = bf16(f2w)                           (8192 float4)
//  [672,675) y1bias[l] = f1b + f1w[:,512:] @ pde[l]
//  675       cvec + psum zero
// ---------------------------------------------------------------------------
__global__ __launch_bounds__(256) void prep_misc(
    const float* __restrict__ cf_w, const float* __restrict__ cf_b,
    const float* __restrict__ sib, const float* __restrict__ proj_w,
    const float* __restrict__ f1w, const float* __restrict__ f1b,
    const float* __restrict__ f2w, const float* __restrict__ pde,
    u16* __restrict__ wsum_b, u16* __restrict__ projw_b,
    u16* __restrict__ f1w512b, u16* __restrict__ f2wb,
    float* __restrict__ cvec, float* __restrict__ psum,
    float* __restrict__ y1bias)
{
  const int b = blockIdx.x, t = threadIdx.x;
  if (b < 256) {
    const int idx = b * 256 + t;
    const float4 a = ((const float4*)cf_w)[idx];
    const float4 c = ((const float4*)(cf_w + 262144))[idx];
    ushort4 o = { f2b(a.x + c.x), f2b(a.y + c.y), f2b(a.z + c.z), f2b(a.w + c.w) };
    ((ushort4*)wsum_b)[idx] = o;
  } else if (b < 512) {
    const int idx = (b - 256) * 256 + t;
    const float4 v = ((const float4*)proj_w)[idx];
    ushort4 o = { f2b(v.x), f2b(v.y), f2b(v.z), f2b(v.w) };
    ((ushort4*)projw_b)[idx] = o;
  } else if (b < 640) {
    const int fi = (b - 512) * 256 + t;          // 0..32767
    const int row = fi >> 7, c4 = fi & 127;
    const float4 v = *(const float4*)(f1w + (size_t)row * 640 + c4 * 4);
    ushort4 o = { f2b(v.x), f2b(v.y), f2b(v.z), f2b(v.w) };
    ((ushort4*)f1w512b)[row * 128 + c4] = o;
  } else if (b < 672) {
    const int idx = (b - 640) * 256 + t;
    const float4 v = ((const float4*)f2w)[idx];
    ushort4 o = { f2b(v.x), f2b(v.y), f2b(v.z), f2b(v.w) };
    ((ushort4*)f2wb)[idx] = o;
  } else if (b < 675) {
    const int l = b - 672, j = t;
    const float* wrow = f1w + (size_t)j * 640 + 512;
    const float* p = pde + l * 128;
    float s = f1b[j];
    #pragma unroll 4
    for (int k = 0; k < 128; ++k) s += wrow[k] * p[k];
    y1bias[l * 256 + j] = s;
  } else {
    cvec[t]       = cf_b[t]       + cf_b[512 + t]       + SIB_SCALE_F * (sib[t]       + sib[512 + t]);
    cvec[256 + t] = cf_b[256 + t] + cf_b[768 + t] + SIB_SCALE_F * (sib[256 + t] + sib[768 + t]);
    if (t < 3) psum[t] = 0.f;
  }
}

// ---------------------------------------------------------------------------
// batched policy input over 3 levels: row g = l*4096+n
// X[g] = bf16( LN(S_l[n]/2^l + 0.01*dep_l)*g+b )   (stride 512)
// ---------------------------------------------------------------------------
__global__ __launch_bounds__(256) void mean_ln_concat_b(
    const float* __restrict__ S0, const float* __restrict__ S1,
    const float* __restrict__ S2,
    const float* __restrict__ dep,
    const float* __restrict__ g, const float* __restrict__ b,
    u16* __restrict__ X)
{
  const int wid = threadIdx.x >> 6, lane = threadIdx.x & 63;
  const int gr = blockIdx.x * 4 + wid;          // 0..12287
  const int l = gr >> 12, n = gr & 4095;
  const float* Sr = (l == 0 ? S0 : l == 1 ? S1 : S2) + (size_t)n * 512;
  const float invM = (l == 0 ? 1.f : l == 1 ? 0.5f : 0.25f);
  const float* depl = dep + 512 * l;
  const int c0 = lane * 8;
  float x[8];
  float s = 0.f, sq = 0.f;
  #pragma unroll
  for (int i = 0; i < 8; ++i) {
    const float v = Sr[c0 + i] * invM + 0.01f * depl[c0 + i];
    x[i] = v; s += v; sq += v * v;
  }
  s = wred(s); sq = wred(sq);
  const float mean = s * (1.f / 512.f);
  const float var = sq * (1.f / 512.f) - mean * mean;
  const float rs = rsqrtf(var + 1e-5f);
  ushort4 o0, o1;
  o0.x = f2b((x[0] - mean) * rs * g[c0 + 0] + b[c0 + 0]);
  o0.y = f2b((x[1] - mean) * rs * g[c0 + 1] + b[c0 + 1]);
  o0.z = f2b((x[2] - mean) * rs * g[c0 + 2] + b[c0 + 2]);
  o0.w = f2b((x[3] - mean) * rs * g[c0 + 3] + b[c0 + 3]);
  o1.x = f2b((x[4] - mean) * rs * g[c0 + 4] + b[c0 + 4]);
  o1.y = f2b((x[5] - mean) * rs * g[c0 + 5] + b[c0 + 5]);
  o1.z = f2b((x[6] - mean) * rs * g[c0 + 6] + b[c0 + 6]);
  o1.w = f2b((x[7] - mean) * rs * g[c0 + 7] + b[c0 + 7]);
  ushort4* Xr = (ushort4*)(X + (size_t)gr * 512);
  Xr[lane * 2]     = o0;
  Xr[lane * 2 + 1] = o1;
}

// LN + relu over 256 cols, fp32 in -> bf16 out (feeds MFMA GEMM)
__global__ __launch_bounds__(256) void ln_relu_b256(
    const float* __restrict__ X, const float* __restrict__ g,
    const float* __restrict__ b, u16* __restrict__ O)
{
  const int wid = threadIdx.x >> 6, lane = threadIdx.x & 63;
  const int n = blockIdx.x * 4 + wid;
  const float* Xr = X + (size_t)n * 256;
  float x[4];
  float s = 0.f, sq = 0.f;
  #pragma unroll
  for (int i = 0; i < 4; ++i) {
    x[i] = Xr[lane * 4 + i]; s += x[i]; sq += x[i] * x[i];
  }
  s = wred(s); sq = wred(sq);
  const float mean = s * (1.f / 256.f);
  const float var = sq * (1.f / 256.f) - mean * mean;
  const float rs = rsqrtf(var + 1e-5f);
  ushort4 o;
  o.x = f2b(fmaxf((x[0] - mean) * rs * g[lane * 4 + 0] + b[lane * 4 + 0], 0.f));
  o.y = f2b(fmaxf((x[1] - mean) * rs * g[lane * 4 + 1] + b[lane * 4 + 1], 0.f));
  o.z = f2b(fmaxf((x[2] - mean) * rs * g[lane * 4 + 2] + b[lane * 4 + 2], 0.f));
  o.w = f2b(fmaxf((x[3] - mean) * rs * g[lane * 4 + 3] + b[lane * 4 + 3], 0.f));
  ((ushort4*)(O + (size_t)n * 256))[lane] = o;
}

// LN + relu over 128 cols, fp32 in-place
__global__ __launch_bounds__(256) void ln_relu128(
    float* __restrict__ X, const float* __restrict__ g, const float* __restrict__ b)
{
  const int wid = threadIdx.x >> 6, lane = threadIdx.x & 63;
  const int n = blockIdx.x * 4 + wid;
  float* Xr = X + (size_t)n * 128;
  float x[2];
  float s = 0.f, sq = 0.f;
  #pragma unroll
  for (int i = 0; i < 2; ++i) {
    x[i] = Xr[lane * 2 + i]; s += x[i]; sq += x[i] * x[i];
  }
  s = wred(s); sq = wred(sq);
  const float mean = s * (1.f / 128.f);
  const float var = sq * (1.f / 128.f) - mean * mean;
  const float rs = rsqrtf(var + 1e-5f);
  #pragma unroll
  for (int i = 0; i < 2; ++i) {
    const int c = lane * 2 + i;
    Xr[c] = fmaxf((x[i] - mean) * rs * g[c] + b[c], 0.f);
  }
}

__global__ __launch_bounds__(256) void policy_reduce_b(
    const float* __restrict__ Y2, const float* __restrict__ pw,
    const float* __restrict__ pb, float* __restrict__ psum)
{
  __shared__ float part[4];
  const int wid = threadIdx.x >> 6, lane = threadIdx.x & 63;
  const int gr = blockIdx.x * 4 + wid;
  const float* r = Y2 + (size_t)gr * 128;
  float z = r[lane * 2] * pw[lane * 2] + r[lane * 2 + 1] * pw[lane * 2 + 1];
  z = wred(z);
  if (lane == 0) {
    const float p = 1.f / (1.f + expf(-(z + pb[0])));
    part[wid] = fminf(fmaxf(p, 1e-7f), 1.f - 1e-7f);
  }
  __syncthreads();
  if (threadIdx.x == 0)
    atomicAdd(psum + (gr >> 12), part[0] + part[1] + part[2] + part[3]);
}

__global__ void finalize_coef(const float* __restrict__ psum, float* __restrict__ coef)
{
  float alive = 1.f, cnt = 1.f;
  #pragma unroll
  for (int l = 0; l < 3; ++l) {
    const float pm = psum[l] * (1.f / 4096.f);
    if (!(pm >= 0.5f)) alive = 0.f;
    coef[l] = alive;
    cnt += alive * (float)(2 << l);
  }
  coef[3] = 1.f / fmaxf(cnt, 1e-8f);
}

__global__ __launch_bounds__(256) void pool_to_bf16(
    const float* __restrict__ h0, const float* __restrict__ S1,
    const float* __restrict__ S2, const float* __restrict__ S3,
    const float* __restrict__ coef, u16* __restrict__ P)
{
  const int idx = blockIdx.x * 256 + threadIdx.x;   // over 4096*512/4
  const float c0 = coef[0], c1 = coef[1], c2 = coef[2], inv = coef[3];
  const float4 a  = ((const float4*)h0)[idx];
  const float4 s1 = ((const float4*)S1)[idx];
  const float4 s2 = ((const float4*)S2)[idx];
  const float4 s3 = ((const float4*)S3)[idx];
  ushort4 o;
  o.x = f2b((a.x + c0 * s1.x + c1 * s2.x + c2 * s3.x) * inv);
  o.y = f2b((a.y + c0 * s1.y + c1 * s2.y + c2 * s3.y) * inv);
  o.z = f2b((a.z + c0 * s1.z + c1 * s2.z + c2 * s3.z) * inv);
  o.w = f2b((a.w + c0 * s1.w + c1 * s2.w + c2 * s3.w) * inv);
  ((ushort4*)P)[idx] = o;
}

__global__ __launch_bounds__(256) void f32_to_bf16_vec(
    const float* __restrict__ src, u16* __restrict__ dst, int n4)
{
  const int idx = blockIdx.x * 256 + threadIdx.x;
  if (idx >= n4) return;
  const float4 v = ((const float4*)src)[idx];
  ushort4 o = { f2b(v.x), f2b(v.y), f2b(v.z), f2b(v.w) };
  ((ushort4*)dst)[idx] = o;
}

// ---------------------------------------------------------------------------
extern "C" void kernel_launch(void* const* d_in, const int* in_sizes, int n_in,
                              void* d_out, int out_size, void* d_ws, size_t ws_size,
                              hipStream_t stream) {
  const int*   tok    = (const int*)  d_in[0];
  const float* emb    = (const float*)d_in[1];
  const float* proj_w = (const float*)d_in[2];
  const float* proj_b = (const float*)d_in[3];
  const float* cf_w   = (const float*)d_in[4];
  const float* cf_b   = (const float*)d_in[5];
  const float* in_g   = (const float*)d_in[6];
  const float* in_b   = (const float*)d_in[7];
  const float* pde    = (const float*)d_in[8];
  const float* f1w    = (const float*)d_in[9];
  const float* f1b    = (const float*)d_in[10];
  const float* n1g    = (const float*)d_in[11];
  const float* n1b    = (const float*)d_in[12];
  const float* f2w    = (const float*)d_in[13];
  const float* f2bias = (const float*)d_in[14];
  const float* n2g    = (const float*)d_in[15];
  const float* n2b    = (const float*)d_in[16];
  const float* pow_w  = (const float*)d_in[17];
  const float* pow_b  = (const float*)d_in[18];
  const float* sib    = (const float*)d_in[19];
  const float* dep    = (const float*)d_in[20];
  const float* out_w  = (const float*)d_in[21];
  const float* out_b  = (const float*)d_in[22];
  float* out = (float*)d_out;

  char* ws = (char*)d_ws;
  size_t off = 0;
  auto alloc = [&](size_t bytes) -> void* {
    void* p = ws + off;
    off += (bytes + 255) & ~(size_t)255;
    return p;
  };
  u16*   outw_b  = (u16*)  alloc((size_t)32000 * 512 * 2);
  u16*   projw_b = (u16*)  alloc((size_t)512 * 512 * 2);
  u16*   wsum_b  = (u16*)  alloc((size_t)512 * 512 * 2);
  u16*   f1w512b = (u16*)  alloc((size_t)256 * 512 * 2);
  u16*   f2wb    = (u16*)  alloc((size_t)128 * 256 * 2);
  float* h0f     = (float*)alloc((size_t)4096 * 512 * 4);
  u16*   h0b     = (u16*)  alloc((size_t)4096 * 512 * 2);
  float* S1f     = (float*)alloc((size_t)4096 * 512 * 4);
  u16*   S1b     = (u16*)  alloc((size_t)4096 * 512 * 2);
  float* S2f     = (float*)alloc((size_t)4096 * 512 * 4);
  u16*   S2b     = (u16*)  alloc((size_t)4096 * 512 * 2);
  float* S3f     = (float*)alloc((size_t)4096 * 512 * 4);
  u16*   S3b     = (u16*)  alloc((size_t)4096 * 512 * 2);
  u16*   X       = (u16*)  alloc((size_t)12288 * 512 * 2);
  float* Y1      = (float*)alloc((size_t)12288 * 256 * 4);
  u16*   Y1b     = (u16*)  alloc((size_t)12288 * 256 * 2);
  float* Y2      = (float*)alloc((size_t)12288 * 128 * 4);
  float* y1bias  = (float*)alloc(3 * 256 * 4);
  float* cvec    = (float*)alloc(512 * 4);
  float* psum    = (float*)alloc(256);
  float* coef    = (float*)alloc(256);
  u16*   poolb   = (u16*)  alloc((size_t)4096 * 512 * 2);

  // all weight prep in two launches
  prep_misc<<<676, 256, 0, stream>>>(cf_w, cf_b, sib, proj_w, f1w, f1b, f2w, pde,
                                     wsum_b, projw_b, f1w512b, f2wb,
                                     cvec, psum, y1bias);
  f32_to_bf16_vec<<<16000, 256, 0, stream>>>(out_w, outw_b, 4096000);

  // h0 = emb[tok] @ proj_w^T + proj_b   (gather fused into A-staging)
  gemm_bf16_bt<true><<<dim3(32, 4), 256, 0, stream>>>(
      emb, tok, nullptr, projw_b, proj_b, 0, 1.f, h0f, h0b, 4096, 512, 512);
  // S_{l+1} = S_l @ (W_L+W_R)^T + 2^l * c
  gemm_bf16_bt<false><<<dim3(32, 4), 256, 0, stream>>>(
      nullptr, nullptr, h0b, wsum_b, cvec, 0, 1.f, S1f, S1b, 4096, 512, 512);
  gemm_bf16_bt<false><<<dim3(32, 4), 256, 0, stream>>>(
      nullptr, nullptr, S1b, wsum_b, cvec, 0, 2.f, S2f, S2b, 4096, 512, 512);
  gemm_bf16_bt<false><<<dim3(32, 4), 256, 0, stream>>>(
      nullptr, nullptr, S2b, wsum_b, cvec, 0, 4.f, S3f, S3b, 4096, 512, 512);

  // policy, 3 levels batched as M=12288, MLP GEMMs in bf16 MFMA
  mean_ln_concat_b<<<3072, 256, 0, stream>>>(h0f, S1f, S2f, dep, in_g, in_b, X);
  gemm_bf16_bt<false><<<dim3(96, 2), 256, 0, stream>>>(
      nullptr, nullptr, X, f1w512b, y1bias, 256, 1.f, Y1, nullptr, 12288, 256, 512);
  ln_relu_b256<<<3072, 256, 0, stream>>>(Y1, n1g, n1b, Y1b);
  gemm_bf16_bt<false><<<dim3(96, 1), 256, 0, stream>>>(
      nullptr, nullptr, Y1b, f2wb, f2bias, 0, 1.f, Y2, nullptr, 12288, 128, 256);
  ln_relu128<<<3072, 256, 0, stream>>>(Y2, n2g, n2b);
  policy_reduce_b<<<3072, 256, 0, stream>>>(Y2, pow_w, pow_b, psum);
  finalize_coef<<<1, 1, 0, stream>>>(psum, coef);

  // pooled = (h0 + a1*S1 + a2*S2 + a3*S3) / cnt  -> bf16
  pool_to_bf16<<<2048, 256, 0, stream>>>(h0f, S1f, S2f, S3f, coef, poolb);

  // out = pooled @ out_w^T + out_b   (4096 x 32000 x 512), 8-phase 256^2
  gemm256_bt<<<dim3(16, 125), 512, 0, stream>>>(poolb, outw_b, out_b,
                                                out, 4096, 32000, 512);
}